// Round 2
// baseline (577.015 us; speedup 1.0000x reference)
//
#include <hip/hip_runtime.h>
#include <hip/hip_cooperative_groups.h>
#include <hip/hip_bf16.h>
#include <math.h>

namespace cg = cooperative_groups;

// Problem constants
#define BATCH 4
#define SEQL 256          // L = C = 256
#define DMODEL 1024
#define DINNER 2048
#define DSTATE 16
#define OUTC 1024
#define NROWS (BATCH * SEQL)   // 1024
#define NCHUNK 4
#define CH 64             // SEQL / NCHUNK
#define NBLK 256          // cooperative grid: 1 block per CU
#define XPZ 32            // x_proj split-K factor

typedef __attribute__((ext_vector_type(8))) short bf16x8;  // 8 bf16 = 4 VGPRs
typedef __attribute__((ext_vector_type(4))) float f32x4;   // MFMA C/D

struct MParams {
    const float *x1, *w_in, *conv_w, *conv_b, *w_xp, *w_dt, *dt_b, *A_log, *Dp, *w_out, *ln_w, *ln_b;
    float *out;
    __hip_bfloat16 *xa, *wb1, *wpb, *wob, *wdb, *xsb, *ybb, *xdblb;
    float *xz, *xs, *xdbl, *xpart, *delta, *carryL, *carryP, *opart;
};

// ---------------------------------------------------------------------------
// 16-lane row sum via DPP row_ror rotations (no DS ops).
// ---------------------------------------------------------------------------
__device__ __forceinline__ float row_reduce16(float x) {
    x += __int_as_float(__builtin_amdgcn_update_dpp(0, __float_as_int(x), 0x128, 0xF, 0xF, true));
    x += __int_as_float(__builtin_amdgcn_update_dpp(0, __float_as_int(x), 0x124, 0xF, 0xF, true));
    x += __int_as_float(__builtin_amdgcn_update_dpp(0, __float_as_int(x), 0x122, 0xF, 0xF, true));
    x += __int_as_float(__builtin_amdgcn_update_dpp(0, __float_as_int(x), 0x121, 0xF, 0xF, true));
    return x;
}

// ---------------------------------------------------------------------------
// One 128x128 output tile of C = A @ B^T (bf16 MFMA), K-range [kbase,kbase+Kpart).
// 4-deep LDS pipeline, counted vmcnt (never 0 mid-loop), raw s_barrier.
// DTSP: fused bias+softplus epilogue (dt_proj). Requires vmcnt==0 on entry
// (guaranteed: called right after grid.sync / block start).
// ---------------------------------------------------------------------------
template <bool DTSP>
__device__ __forceinline__ void gemm_tile(const __hip_bfloat16* __restrict__ A,
                                          const __hip_bfloat16* __restrict__ B,
                                          float* __restrict__ Cz,
                                          const int N, const int lda, const int ldb,
                                          const int m0, const int n0,
                                          const int kbase, const int Kpart,
                                          const float* __restrict__ bd,
                                          __hip_bfloat16* __restrict__ As,
                                          __hip_bfloat16* __restrict__ Bs) {
    const int t  = threadIdx.x;
    const int w  = t >> 6;          // wave 0..3
    const int ln = t & 63;
    const int wm = w >> 1, wn = w & 1;
    const int q  = ln >> 4, lr = ln & 15;

    f32x4 acc[4][4] = {};
    const __hip_bfloat16* Ag = A + (size_t)m0 * lda + kbase;
    const __hip_bfloat16* Bg = B + (size_t)n0 * ldb + kbase;

    auto stage = [&](int k0, int buf) {
        #pragma unroll
        for (int i = 0; i < 2; ++i) {
            const int c = (i * 4 + w) * 64 + ln;
            const int r = c >> 2, col = (c & 3) * 8;
            __builtin_amdgcn_global_load_lds(
                (const __attribute__((address_space(1))) void*)(Ag + (size_t)r * lda + k0 + col),
                (__attribute__((address_space(3))) void*)(As + buf * 4096 + (i * 4 + w) * 512),
                16, 0, 0);
            __builtin_amdgcn_global_load_lds(
                (const __attribute__((address_space(1))) void*)(Bg + (size_t)r * ldb + k0 + col),
                (__attribute__((address_space(3))) void*)(Bs + buf * 4096 + (i * 4 + w) * 512),
                16, 0, 0);
        }
    };

    const int nk = Kpart / 32;
    for (int s = 0; s < 3 && s < nk; ++s) stage(s * 32, s);

    for (int kk = 0; kk < nk; ++kk) {
        const int last = (kk + 2 < nk - 1) ? (kk + 2) : (nk - 1);
        const int nf = last - kk;      // younger stages to keep in flight
        if (nf >= 2)      asm volatile("s_waitcnt vmcnt(8)" ::: "memory");
        else if (nf == 1) asm volatile("s_waitcnt vmcnt(4)" ::: "memory");
        else              asm volatile("s_waitcnt vmcnt(0)" ::: "memory");
        __builtin_amdgcn_s_barrier();
        if (kk + 3 < nk) stage((kk + 3) * 32, (kk + 3) & 3);

        const __hip_bfloat16* Ab = As + (kk & 3) * 4096;
        const __hip_bfloat16* Bb = Bs + (kk & 3) * 4096;
        bf16x8 af[4], bfr[4];
        #pragma unroll
        for (int i = 0; i < 4; ++i)
            af[i] = *(const bf16x8*)(Ab + (wm * 64 + i * 16 + lr) * 32 + q * 8);
        #pragma unroll
        for (int j = 0; j < 4; ++j)
            bfr[j] = *(const bf16x8*)(Bb + (wn * 64 + j * 16 + lr) * 32 + q * 8);
        #pragma unroll
        for (int i = 0; i < 4; ++i)
            #pragma unroll
            for (int j = 0; j < 4; ++j)
                acc[i][j] = __builtin_amdgcn_mfma_f32_16x16x32_bf16(af[i], bfr[j], acc[i][j], 0, 0, 0);
    }
    #pragma unroll
    for (int i = 0; i < 4; ++i) {
        const int mrow = m0 + wm * 64 + i * 16 + q * 4;
        #pragma unroll
        for (int j = 0; j < 4; ++j) {
            const int ncol = n0 + wn * 64 + j * 16 + lr;
            if (DTSP) {
                const float bias = bd[ncol];
                #pragma unroll
                for (int r = 0; r < 4; ++r) {
                    float v = acc[i][j][r] + bias;
                    float sp = (v > 20.f) ? v : log1pf(__expf(v));
                    Cz[(size_t)(mrow + r) * N + ncol] = sp;
                }
            } else {
                #pragma unroll
                for (int r = 0; r < 4; ++r)
                    Cz[(size_t)(mrow + r) * N + ncol] = acc[i][j][r];
            }
        }
    }
}

// ---------------------------------------------------------------------------
// Cast ranges
// ---------------------------------------------------------------------------
#define R0 (1024 * 1024)
#define R1 (R0 + 4096 * 1024)
#define R2 (R1 + 2048 * 1024)
#define R3 (R2 + 128 * 2048)
#define R4 (R3 + 2048 * 64)

// ---------------------------------------------------------------------------
// The whole pipeline as ONE cooperative kernel. 256 blocks (1/CU) x 256 thr.
// grid.sync() between phases replaces 9 kernel-launch boundaries.
// LDS: 64 KB union (GEMM 4-stage dbuf / scan tiles / ln scratch).
// ---------------------------------------------------------------------------
__global__ __launch_bounds__(256) void mega(MParams p) {
    cg::grid_group grid = cg::this_grid();
    __shared__ __align__(16) char smem[65536];
    __hip_bfloat16* As = (__hip_bfloat16*)smem;           // 32 KB (4 x 8 KB)
    __hip_bfloat16* Bs = (__hip_bfloat16*)(smem + 32768); // 32 KB
    const int lin = blockIdx.x;
    const int t = threadIdx.x;

    // ---- phase 0: fused fp32->bf16 casts -------------------------------
    for (int i = lin * 256 + t; i < R4; i += NBLK * 256) {
        if (i < R0) {
            p.xa[i] = __float2bfloat16(p.x1[i]);
        } else if (i < R1) {
            int j = i - R0; p.wb1[j] = __float2bfloat16(p.w_in[j]);
        } else if (i < R2) {
            int j = i - R1; p.wob[j] = __float2bfloat16(p.w_out[j]);
        } else if (i < R3) {
            int j = i - R2; int e = j >> 11;
            p.wpb[j] = __float2bfloat16(e < 96 ? p.w_xp[j] : 0.f);
        } else {
            int j = i - R3; p.wdb[j] = __float2bfloat16(p.w_dt[j]);
        }
    }
    grid.sync();

    // ---- phase 1: in_proj  xz = xa @ wb1^T  (1024x4096, K=1024) --------
    {
        const int s = (lin & 7) * 32 + (lin >> 3);        // XCD swizzle (bijective, 256%8==0)
        const int bx = s & 31, by = s >> 5;               // 32 n-tiles x 8 m-tiles
        gemm_tile<false>(p.xa, p.wb1, p.xz, 4096, 1024, 1024,
                         by * 128, bx * 128, 0, 1024, nullptr, As, Bs);
    }
    grid.sync();

    // ---- phase 2: depthwise causal conv1d + SiLU -> xs, xsb ------------
    for (int idx = lin * 256 + t; idx < NROWS * DINNER; idx += NBLK * 256) {
        int d = idx & (DINNER - 1);
        int l = (idx >> 11) & (SEQL - 1);
        int b = idx >> 19;
        const float w0 = p.conv_w[d * 4 + 0];
        const float w1 = p.conv_w[d * 4 + 1];
        const float w2 = p.conv_w[d * 4 + 2];
        const float w3 = p.conv_w[d * 4 + 3];
        float acc = p.conv_b[d];
        const size_t base = (size_t)(b * SEQL) * (2 * DINNER) + d;
        if (l >= 3) acc += w0 * p.xz[base + (size_t)(l - 3) * (2 * DINNER)];
        if (l >= 2) acc += w1 * p.xz[base + (size_t)(l - 2) * (2 * DINNER)];
        if (l >= 1) acc += w2 * p.xz[base + (size_t)(l - 1) * (2 * DINNER)];
        acc += w3 * p.xz[base + (size_t)l * (2 * DINNER)];
        float v = acc / (1.f + __expf(-acc));
        p.xs[idx] = v;
        p.xsb[idx] = __float2bfloat16(v);
    }
    grid.sync();

    // ---- phase 3: x_proj  xpart[z] = xsb @ wpb^T  (split-K 32) ---------
    {
        const int z = lin & 31, by = lin >> 5;            // 32 K-slices x 8 m-tiles
        float* Cz = p.xpart + (size_t)z * (1024 * 128);
        gemm_tile<false>(p.xsb, p.wpb, Cz, 128, 2048, 2048,
                         by * 128, 0, z * 64, 64, nullptr, As, Bs);
    }
    grid.sync();

    // ---- phase 4: reduce 32 partials -> xdbl (fp32) + xdblb (bf16) -----
    for (int i = lin * 256 + t; i < 1024 * 128; i += NBLK * 256) {
        float s = 0.f;
        #pragma unroll
        for (int z = 0; z < XPZ; ++z) s += p.xpart[(size_t)z * (1024 * 128) + i];
        p.xdbl[i] = s;
        p.xdblb[i] = __float2bfloat16(s);
    }
    grid.sync();

    // ---- phase 5: dt_proj + softplus -> delta (128 tiles; half idle) ---
    if (lin < 128) {
        const int bx = lin & 15, by = lin >> 4;           // 16 n-tiles x 8 m-tiles
        gemm_tile<true>(p.xdblb, p.wdb, p.delta, 2048, 128, 64,
                        by * 128, bx * 128, 0, 64, p.dt_b, As, Bs);
    }
    grid.sync();

    // ---- phase 6: scan A — per-chunk carries ---------------------------
    {
        float (*sDU)[16][2] = (float(*)[16][2])smem;            // 8 KB
        float (*sB)[16]     = (float(*)[16])(smem + 8192);      // 4 KB
        const int dl = t >> 4, n = t & 15;
        const int srow = t >> 4, scol = t & 15;
        for (int v = lin; v < (DINNER / 16) * BATCH * NCHUNK; v += NBLK) {
            const int dg = v & 127, b = (v >> 7) & 3, c = v >> 9;
            const int d = dg * 16 + dl;
            const float a = -__expf(p.A_log[d * DSTATE + n]);
            const int sd = dg * 16 + scol;
            const int rowbase = b * SEQL + c * CH;
            __syncthreads();   // protect smem reuse across virtual blocks
            #pragma unroll
            for (int i = 0; i < 4; ++i) {
                const int row = rowbase + i * 16 + srow;
                const float dv = p.delta[(size_t)row * DINNER + sd];
                const float xv = p.xs[(size_t)row * DINNER + sd];
                sDU[i * 16 + srow][scol][0] = dv;
                sDU[i * 16 + srow][scol][1] = dv * xv;
                sB[i * 16 + srow][scol] = p.xdbl[row * 128 + 64 + scol];
            }
            __syncthreads();
            float h = 0.f, P = 1.f;
            #pragma unroll 16
            for (int l = 0; l < CH; ++l) {
                const float e = __expf(sDU[l][dl][0] * a);
                h = e * h + sDU[l][dl][1] * sB[l][n];
                P *= e;
            }
            const size_t ci = (((size_t)(b * NCHUNK + c)) * DINNER + d) * DSTATE + n;
            p.carryL[ci] = h;
            p.carryP[ci] = P;
        }
    }
    grid.sync();

    // ---- phase 7: scan B — combine carries + apply + gate -> ybb -------
    {
        float (*sDU)[16][2] = (float(*)[16][2])smem;            // 8 KB
        float (*sBC)[16][2] = (float(*)[16][2])(smem + 8192);   // 8 KB
        float (*sGW)[16][2] = (float(*)[16][2])(smem + 16384);  // 8 KB
        const int dl = t >> 4, n = t & 15;
        const int srow = t >> 4, scol = t & 15;
        for (int v = lin; v < (DINNER / 16) * BATCH * NCHUNK; v += NBLK) {
            const int dg = v & 127, b = (v >> 7) & 3, c = v >> 9;
            const int d = dg * 16 + dl;
            const float a = -__expf(p.A_log[d * DSTATE + n]);
            const int sd = dg * 16 + scol;
            const float Dstage = p.Dp[sd];
            const int rowbase = b * SEQL + c * CH;
            __syncthreads();
            #pragma unroll
            for (int i = 0; i < 4; ++i) {
                const int row = rowbase + i * 16 + srow;
                const float dv = p.delta[(size_t)row * DINNER + sd];
                const float xv = p.xs[(size_t)row * DINNER + sd];
                const float r  = p.xz[(size_t)row * (2 * DINNER) + DINNER + sd];
                const float g = r / (1.f + __expf(-r));
                const int lr_ = i * 16 + srow;
                sDU[lr_][scol][0] = dv;
                sDU[lr_][scol][1] = dv * xv;
                sGW[lr_][scol][0] = g;
                sGW[lr_][scol][1] = Dstage * xv * g;
                sBC[lr_][scol][0] = p.xdbl[row * 128 + 64 + scol];
                sBC[lr_][scol][1] = p.xdbl[row * 128 + 80 + scol];
            }
            __syncthreads();
            float h = 0.f;
            for (int j = 0; j < c; ++j) {
                const size_t ci = (((size_t)(b * NCHUNK + j)) * DINNER + d) * DSTATE + n;
                h = p.carryP[ci] * h + p.carryL[ci];
            }
            #pragma unroll 16
            for (int l = 0; l < CH; ++l) {
                const float e = __expf(sDU[l][dl][0] * a);
                h = e * h + sDU[l][dl][1] * sBC[l][n][0];
                float pr = row_reduce16(h * sBC[l][n][1]);
                if (n == 0) {
                    const float y = pr * sGW[l][dl][0] + sGW[l][dl][1];
                    p.ybb[(size_t)(rowbase + l) * DINNER + d] = __float2bfloat16(y);
                }
            }
        }
    }
    grid.sync();

    // ---- phase 8: out_proj  opart[z] = ybb @ wob^T (split-K 4) ---------
    {
        const int s = (lin & 7) * 32 + (lin >> 3);        // XCD swizzle
        const int bx = s & 7, by = (s >> 3) & 7, z = s >> 6;
        float* Cz = p.opart + (size_t)z * (1024 * 1024);
        gemm_tile<false>(p.ybb, p.wob, Cz, 1024, 2048, 2048,
                         by * 128, bx * 128, z * 512, 512, nullptr, As, Bs);
    }
    grid.sync();

    // ---- phase 9: LayerNorm (+4-way split-K reduce) -> out -------------
    {
        float* red = (float*)smem;
        for (int row = lin; row < NROWS; row += NBLK) {
            __syncthreads();   // protect red reuse across virtual rows
            float vv[4];
            float s = 0.f, s2 = 0.f;
            #pragma unroll
            for (int i = 0; i < 4; ++i) {
                const int c = t + 256 * i;
                float acc = 0.f;
                #pragma unroll
                for (int z = 0; z < 4; ++z)
                    acc += p.opart[(size_t)z * (1024 * 1024) + (size_t)row * OUTC + c];
                vv[i] = acc;
                s += acc;
                s2 += acc * acc;
            }
            #pragma unroll
            for (int o = 32; o; o >>= 1) {
                s += __shfl_down(s, o);
                s2 += __shfl_down(s2, o);
            }
            const int wid = t >> 6;
            if ((t & 63) == 0) { red[wid] = s; red[4 + wid] = s2; }
            __syncthreads();
            if (t == 0) {
                float ts = red[0] + red[1] + red[2] + red[3];
                float ts2 = red[4] + red[5] + red[6] + red[7];
                float mu = ts * (1.f / OUTC);
                float var = ts2 * (1.f / OUTC) - mu * mu;
                red[0] = mu;
                red[1] = rsqrtf(var + 1e-5f);
            }
            __syncthreads();
            const float mu = red[0], rs = red[1];
            #pragma unroll
            for (int i = 0; i < 4; ++i) {
                const int c = t + 256 * i;
                p.out[(size_t)row * OUTC + c] = (vv[i] - mu) * rs * p.ln_w[c] + p.ln_b[c];
            }
        }
    }
}

// ---------------------------------------------------------------------------
extern "C" void kernel_launch(void* const* d_in, const int* in_sizes, int n_in,
                              void* d_out, int out_size, void* d_ws, size_t ws_size,
                              hipStream_t stream) {
    MParams h;
    h.x1        = (const float*)d_in[0];   // (1024,1024)
    h.w_in      = (const float*)d_in[1];   // (4096,1024)
    h.conv_w    = (const float*)d_in[2];   // (2048,1,4)
    h.conv_b    = (const float*)d_in[3];   // (2048,)
    h.w_xp      = (const float*)d_in[4];   // (96,2048)
    h.w_dt      = (const float*)d_in[5];   // (2048,64)
    h.dt_b      = (const float*)d_in[6];   // (2048,)
    h.A_log     = (const float*)d_in[7];   // (2048,16)
    h.Dp        = (const float*)d_in[8];   // (2048,)
    h.w_out     = (const float*)d_in[9];   // (1024,2048)
    h.ln_w      = (const float*)d_in[10];  // (1024,)
    h.ln_b      = (const float*)d_in[11];  // (1024,)
    h.out       = (float*)d_out;

    char* p = (char*)d_ws;
    h.xa    = (__hip_bfloat16*)p; p += (size_t)1024 * 1024 * 2;  // 2 MB
    h.wb1   = (__hip_bfloat16*)p; p += (size_t)4096 * 1024 * 2;  // 8 MB
    h.wpb   = (__hip_bfloat16*)p; p += (size_t)128 * 2048 * 2;   // 0.5 MB
    h.wob   = (__hip_bfloat16*)p; p += (size_t)1024 * 2048 * 2;  // 4 MB
    h.wdb   = (__hip_bfloat16*)p; p += (size_t)2048 * 64 * 2;    // 0.25 MB
    h.xsb   = (__hip_bfloat16*)p; p += (size_t)1024 * 2048 * 2;  // 4 MB
    h.ybb   = (__hip_bfloat16*)p; p += (size_t)1024 * 2048 * 2;  // 4 MB
    h.xdblb = (__hip_bfloat16*)p; p += (size_t)1024 * 128 * 2;   // 0.25 MB
    h.xz    = (float*)p; p += (size_t)1024 * 4096 * 4;           // 16 MB
    h.xs    = (float*)p; p += (size_t)1024 * 2048 * 4;           // 8 MB
    h.xdbl  = (float*)p; p += (size_t)1024 * 128 * 4;            // 0.5 MB
    h.xpart = (float*)p; p += (size_t)XPZ * 1024 * 128 * 4;      // 16 MB
    h.delta = (float*)p; p += (size_t)1024 * 2048 * 4;           // 8 MB
    h.carryL = (float*)p; p += (size_t)BATCH * NCHUNK * DINNER * DSTATE * 4; // 2 MB
    h.carryP = (float*)p; p += (size_t)BATCH * NCHUNK * DINNER * DSTATE * 4; // 2 MB
    // out_proj partials (16 MB) alias xz: scan B (last xz reader) precedes
    // out_proj, separated by grid.sync.
    h.opart = h.xz;

    void* args[] = { (void*)&h };
    hipLaunchCooperativeKernel((void*)mega, dim3(NBLK), dim3(256), args, 0, stream);
}

// Round 3
// 237.309 us; speedup vs baseline: 2.4315x; 2.4315x over previous
//
#include <hip/hip_runtime.h>
#include <hip/hip_bf16.h>
#include <math.h>

// Problem constants (from reference)
#define BATCH 4
#define SEQL 256          // L = C = 256
#define DMODEL 1024
#define DINNER 2048
#define DSTATE 16
#define OUTC 1024
#define NROWS (BATCH * SEQL)   // 1024
#define NCHUNK 4
#define CH 64             // SEQL / NCHUNK
#define XPZ 16            // x_proj split-K slices (each 128 d wide)

typedef __attribute__((ext_vector_type(8))) short bf16x8;  // 8 bf16 = 4 VGPRs
typedef __attribute__((ext_vector_type(4))) float f32x4;   // MFMA C/D

// ---------------------------------------------------------------------------
// bf16 MFMA GEMM, C = A @ B^T, split-K over blockIdx.z. 4-deep LDS pipeline,
// counted vmcnt (never 0 mid-loop), raw s_barrier. (verified round 1)
// ---------------------------------------------------------------------------
__global__ __launch_bounds__(256) void gemm_mfma(const __hip_bfloat16* __restrict__ A,
                                                 const __hip_bfloat16* __restrict__ B,
                                                 float* __restrict__ C,
                                                 int M, int N, int K,
                                                 int lda, int ldb) {
    __shared__ __hip_bfloat16 As[4][128 * 32];
    __shared__ __hip_bfloat16 Bs[4][128 * 32];
    const int t  = threadIdx.x;
    const int w  = t >> 6;          // wave 0..3
    const int ln = t & 63;
    const int wm = w >> 1, wn = w & 1;
    const int q  = ln >> 4, lr = ln & 15;
    const int m0 = blockIdx.y * 128;
    const int n0 = blockIdx.x * 128;
    const int Kpart = K / gridDim.z;
    const int kbase = blockIdx.z * Kpart;

    f32x4 acc[4][4] = {};

    const __hip_bfloat16* Ag = A + (size_t)m0 * lda + kbase;
    const __hip_bfloat16* Bg = B + (size_t)n0 * ldb + kbase;

    auto stage = [&](int k0, int buf) {
        #pragma unroll
        for (int i = 0; i < 2; ++i) {
            const int c = (i * 4 + w) * 64 + ln;
            const int r = c >> 2, col = (c & 3) * 8;
            __builtin_amdgcn_global_load_lds(
                (const __attribute__((address_space(1))) void*)(Ag + (size_t)r * lda + k0 + col),
                (__attribute__((address_space(3))) void*)(As[buf] + (i * 4 + w) * 64 * 8),
                16, 0, 0);
            __builtin_amdgcn_global_load_lds(
                (const __attribute__((address_space(1))) void*)(Bg + (size_t)r * ldb + k0 + col),
                (__attribute__((address_space(3))) void*)(Bs[buf] + (i * 4 + w) * 64 * 8),
                16, 0, 0);
        }
    };

    const int nk = Kpart / 32;
    for (int s = 0; s < 3 && s < nk; ++s) stage(s * 32, s);

    for (int kk = 0; kk < nk; ++kk) {
        const int last = (kk + 2 < nk - 1) ? (kk + 2) : (nk - 1);
        const int nf = last - kk;      // younger stages to keep in flight
        if (nf >= 2)      asm volatile("s_waitcnt vmcnt(8)" ::: "memory");
        else if (nf == 1) asm volatile("s_waitcnt vmcnt(4)" ::: "memory");
        else              asm volatile("s_waitcnt vmcnt(0)" ::: "memory");
        __builtin_amdgcn_s_barrier();
        if (kk + 3 < nk) stage((kk + 3) * 32, (kk + 3) & 3);

        const int buf = kk & 3;
        bf16x8 af[4], bfr[4];
        #pragma unroll
        for (int i = 0; i < 4; ++i)
            af[i] = *(const bf16x8*)(As[buf] + (wm * 64 + i * 16 + lr) * 32 + q * 8);
        #pragma unroll
        for (int j = 0; j < 4; ++j)
            bfr[j] = *(const bf16x8*)(Bs[buf] + (wn * 64 + j * 16 + lr) * 32 + q * 8);
        #pragma unroll
        for (int i = 0; i < 4; ++i)
            #pragma unroll
            for (int j = 0; j < 4; ++j)
                acc[i][j] = __builtin_amdgcn_mfma_f32_16x16x32_bf16(af[i], bfr[j], acc[i][j], 0, 0, 0);
    }
    float* Cz = C + (size_t)blockIdx.z * M * N;
    #pragma unroll
    for (int i = 0; i < 4; ++i) {
        const int mrow = m0 + wm * 64 + i * 16 + q * 4;
        #pragma unroll
        for (int j = 0; j < 4; ++j) {
            const int ncol = n0 + wn * 64 + j * 16 + lr;
            #pragma unroll
            for (int r = 0; r < 4; ++r)
                Cz[(size_t)(mrow + r) * N + ncol] = acc[i][j][r];
        }
    }
}

// ---------------------------------------------------------------------------
// x_proj with INLINE depthwise conv + SiLU for the A operand.
// Block = (z K-slice of 128 d, m-tile of 128 rows). B (wpb) staged via
// global_load_lds (4 k-steps upfront); A computed from xz (conv+silu, same
// arithmetic order as the old conv kernel) into LDS while B loads are in
// flight; ONE barrier; 4 k-steps of MFMA; epilogue -> xpart[z].
// Removes the conv kernel and the xs/xsb tensors.
// ---------------------------------------------------------------------------
__global__ __launch_bounds__(256) void xproj_conv(const float* __restrict__ xz,
                                                  const float* __restrict__ conv_w,
                                                  const float* __restrict__ conv_b,
                                                  const __hip_bfloat16* __restrict__ Wp,
                                                  float* __restrict__ xpart) {
    __shared__ __hip_bfloat16 As[4 * 4096];
    __shared__ __hip_bfloat16 Bs[4 * 4096];
    const int t  = threadIdx.x;
    const int w  = t >> 6;
    const int ln = t & 63;
    const int wm = w >> 1, wn = w & 1;
    const int q  = ln >> 4, lr = ln & 15;
    const int z  = blockIdx.x;            // K-slice (d range)
    const int m0 = blockIdx.y * 128;
    const int kbase = z * 128;

    // stage all 4 B k-steps (async, stay in flight under the conv compute)
    const __hip_bfloat16* Bg = Wp + kbase;          // ldb = 2048, n0 = 0
    #pragma unroll
    for (int stg = 0; stg < 4; ++stg) {
        #pragma unroll
        for (int i = 0; i < 2; ++i) {
            const int c = (i * 4 + w) * 64 + ln;
            const int r = c >> 2, col = (c & 3) * 8;
            __builtin_amdgcn_global_load_lds(
                (const __attribute__((address_space(1))) void*)(Bg + (size_t)r * 2048 + stg * 32 + col),
                (__attribute__((address_space(3))) void*)(Bs + stg * 4096 + (i * 4 + w) * 512),
                16, 0, 0);
        }
    }

    // compute A tile: conv+silu for rows m0..m0+127, d in [kbase, kbase+128)
    {
        const int r  = t >> 1;            // 0..127
        const int dh = (t & 1) * 16;      // 0 or 16 within each 32-wide k-step
        const int gr = m0 + r;
        const int bb = gr >> 8, l = gr & 255;
        const float* xrow = xz + (size_t)bb * 256 * 4096;
        #pragma unroll
        for (int stg = 0; stg < 4; ++stg) {
            const int d0 = kbase + stg * 32 + dh;
            #pragma unroll
            for (int j = 0; j < 4; ++j) {
                const int d = d0 + j * 4;
                float4 t0 = {}, t1 = {}, t2 = {}, t3;
                if (l >= 3) t0 = *(const float4*)(xrow + (size_t)(l - 3) * 4096 + d);
                if (l >= 2) t1 = *(const float4*)(xrow + (size_t)(l - 2) * 4096 + d);
                if (l >= 1) t2 = *(const float4*)(xrow + (size_t)(l - 1) * 4096 + d);
                t3 = *(const float4*)(xrow + (size_t)l * 4096 + d);
                const float* p0 = (const float*)&t0;
                const float* p1 = (const float*)&t1;
                const float* p2 = (const float*)&t2;
                const float* p3 = (const float*)&t3;
                #pragma unroll
                for (int u = 0; u < 4; ++u) {
                    const int du = d + u;
                    const float4 wv = *(const float4*)(conv_w + (size_t)du * 4);
                    float acc = conv_b[du];
                    if (l >= 3) acc += wv.x * p0[u];
                    if (l >= 2) acc += wv.y * p1[u];
                    if (l >= 1) acc += wv.z * p2[u];
                    acc += wv.w * p3[u];
                    const float v = acc / (1.f + __expf(-acc));
                    As[stg * 4096 + r * 32 + dh + j * 4 + u] = __float2bfloat16(v);
                }
            }
        }
    }
    __syncthreads();   // drains B loads (vmcnt) + A ds_writes (lgkm) + barrier

    f32x4 acc[4][4] = {};
    #pragma unroll
    for (int kk = 0; kk < 4; ++kk) {
        const __hip_bfloat16* Ab = As + kk * 4096;
        const __hip_bfloat16* Bb = Bs + kk * 4096;
        bf16x8 af[4], bfr[4];
        #pragma unroll
        for (int i = 0; i < 4; ++i)
            af[i] = *(const bf16x8*)(Ab + (wm * 64 + i * 16 + lr) * 32 + q * 8);
        #pragma unroll
        for (int j = 0; j < 4; ++j)
            bfr[j] = *(const bf16x8*)(Bb + (wn * 64 + j * 16 + lr) * 32 + q * 8);
        #pragma unroll
        for (int i = 0; i < 4; ++i)
            #pragma unroll
            for (int j = 0; j < 4; ++j)
                acc[i][j] = __builtin_amdgcn_mfma_f32_16x16x32_bf16(af[i], bfr[j], acc[i][j], 0, 0, 0);
    }
    float* Cz = xpart + (size_t)z * (1024 * 128);
    #pragma unroll
    for (int i = 0; i < 4; ++i) {
        const int mrow = m0 + wm * 64 + i * 16 + q * 4;
        #pragma unroll
        for (int j = 0; j < 4; ++j) {
            const int ncol = wn * 64 + j * 16 + lr;
            #pragma unroll
            for (int r = 0; r < 4; ++r)
                Cz[(size_t)(mrow + r) * 128 + ncol] = acc[i][j][r];
        }
    }
}

// ---------------------------------------------------------------------------
// dt_proj as MFMA GEMM with fused bias + softplus epilogue. (K=64, 2 iters)
// ---------------------------------------------------------------------------
__global__ __launch_bounds__(256) void gemm_dtsp(const __hip_bfloat16* __restrict__ A,
                                                 const __hip_bfloat16* __restrict__ B,
                                                 const float* __restrict__ bd,
                                                 float* __restrict__ delta) {
    __shared__ __hip_bfloat16 As[2][128 * 32];
    __shared__ __hip_bfloat16 Bs[2][128 * 32];
    const int t  = threadIdx.x;
    const int w  = t >> 6;
    const int ln = t & 63;
    const int wm = w >> 1, wn = w & 1;
    const int q  = ln >> 4, lr = ln & 15;
    const int m0 = blockIdx.y * 128;
    const int n0 = blockIdx.x * 128;
    const int lda = 128, ldb = 64, N = 2048;

    f32x4 acc[4][4] = {};
    const __hip_bfloat16* Ag = A + (size_t)m0 * lda;
    const __hip_bfloat16* Bg = B + (size_t)n0 * ldb;

    auto stage = [&](int k0, int buf) {
        #pragma unroll
        for (int i = 0; i < 2; ++i) {
            const int c = (i * 4 + w) * 64 + ln;
            const int r = c >> 2, col = (c & 3) * 8;
            __builtin_amdgcn_global_load_lds(
                (const __attribute__((address_space(1))) void*)(Ag + (size_t)r * lda + k0 + col),
                (__attribute__((address_space(3))) void*)(As[buf] + (i * 4 + w) * 64 * 8),
                16, 0, 0);
            __builtin_amdgcn_global_load_lds(
                (const __attribute__((address_space(1))) void*)(Bg + (size_t)r * ldb + k0 + col),
                (__attribute__((address_space(3))) void*)(Bs[buf] + (i * 4 + w) * 64 * 8),
                16, 0, 0);
        }
    };

    stage(0, 0);
    stage(32, 1);
    #pragma unroll
    for (int kk = 0; kk < 2; ++kk) {
        if (kk == 0) asm volatile("s_waitcnt vmcnt(4)" ::: "memory");
        else         asm volatile("s_waitcnt vmcnt(0)" ::: "memory");
        __builtin_amdgcn_s_barrier();
        bf16x8 af[4], bfr[4];
        #pragma unroll
        for (int i = 0; i < 4; ++i)
            af[i] = *(const bf16x8*)(As[kk] + (wm * 64 + i * 16 + lr) * 32 + q * 8);
        #pragma unroll
        for (int j = 0; j < 4; ++j)
            bfr[j] = *(const bf16x8*)(Bs[kk] + (wn * 64 + j * 16 + lr) * 32 + q * 8);
        #pragma unroll
        for (int i = 0; i < 4; ++i)
            #pragma unroll
            for (int j = 0; j < 4; ++j)
                acc[i][j] = __builtin_amdgcn_mfma_f32_16x16x32_bf16(af[i], bfr[j], acc[i][j], 0, 0, 0);
    }
    #pragma unroll
    for (int i = 0; i < 4; ++i) {
        const int mrow = m0 + wm * 64 + i * 16 + q * 4;
        #pragma unroll
        for (int j = 0; j < 4; ++j) {
            const int ncol = n0 + wn * 64 + j * 16 + lr;
            const float bias = bd[ncol];
            #pragma unroll
            for (int r = 0; r < 4; ++r) {
                float v = acc[i][j][r] + bias;
                float sp = (v > 20.f) ? v : log1pf(__expf(v));
                delta[(size_t)(mrow + r) * N + ncol] = sp;
            }
        }
    }
}

// ---------------------------------------------------------------------------
// Reduce XPZ split-K partials of x_proj -> xdbl fp32 (1024x128) + xdblb bf16.
// ---------------------------------------------------------------------------
__global__ void xdbl_reduce_kernel(const float* __restrict__ part,
                                   float* __restrict__ xdbl,
                                   __hip_bfloat16* __restrict__ xdblb) {
    const int i = blockIdx.x * 256 + threadIdx.x;   // 1024*128
    float s = 0.f;
    #pragma unroll
    for (int z = 0; z < XPZ; ++z) s += part[(size_t)z * (1024 * 128) + i];
    xdbl[i] = s;
    xdblb[i] = __float2bfloat16(s);
}

// ---------------------------------------------------------------------------
// Fused fp32 -> bf16 casts for all weight/activation inputs.
// ---------------------------------------------------------------------------
#define R0 (1024 * 1024)
#define R1 (R0 + 4096 * 1024)
#define R2 (R1 + 2048 * 1024)
#define R3 (R2 + 128 * 2048)
#define R4 (R3 + 2048 * 64)
__global__ void cast_all_kernel(const float* __restrict__ x1,
                                const float* __restrict__ w_in,
                                const float* __restrict__ w_out,
                                const float* __restrict__ w_xp,
                                const float* __restrict__ w_dt,
                                __hip_bfloat16* __restrict__ xa,
                                __hip_bfloat16* __restrict__ wb1,
                                __hip_bfloat16* __restrict__ wob,
                                __hip_bfloat16* __restrict__ wpb,
                                __hip_bfloat16* __restrict__ wdb) {
    int i = blockIdx.x * 256 + threadIdx.x;
    if (i < R0) {
        xa[i] = __float2bfloat16(x1[i]);
    } else if (i < R1) {
        int j = i - R0; wb1[j] = __float2bfloat16(w_in[j]);
    } else if (i < R2) {
        int j = i - R1; wob[j] = __float2bfloat16(w_out[j]);
    } else if (i < R3) {
        int j = i - R2; int e = j >> 11;
        wpb[j] = __float2bfloat16(e < 96 ? w_xp[j] : 0.f);
    } else if (i < R4) {
        int j = i - R3; wdb[j] = __float2bfloat16(w_dt[j]);
    }
}

// ---------------------------------------------------------------------------
// 16-lane row sum via DPP row_ror rotations (no DS ops).
// ---------------------------------------------------------------------------
__device__ __forceinline__ float row_reduce16(float x) {
    x += __int_as_float(__builtin_amdgcn_update_dpp(0, __float_as_int(x), 0x128, 0xF, 0xF, true));
    x += __int_as_float(__builtin_amdgcn_update_dpp(0, __float_as_int(x), 0x124, 0xF, 0xF, true));
    x += __int_as_float(__builtin_amdgcn_update_dpp(0, __float_as_int(x), 0x122, 0xF, 0xF, true));
    x += __int_as_float(__builtin_amdgcn_update_dpp(0, __float_as_int(x), 0x121, 0xF, 0xF, true));
    return x;
}

// ---------------------------------------------------------------------------
// Single-pass selective scan: block = (dg of 16 d, b). Iterates the 4 chunks
// sequentially with h in registers (exact reference recurrence; no carries).
// conv+SiLU for xv computed inline from xz (same arithmetic order as before).
// Also applies +D*xv and *silu(res) gating, writes ybb bf16.
// ---------------------------------------------------------------------------
__global__ __launch_bounds__(256) void scan_fused(const float* __restrict__ delta,
                                                  const float* __restrict__ xz,
                                                  const float* __restrict__ conv_w,
                                                  const float* __restrict__ conv_b,
                                                  const float* __restrict__ xdbl,
                                                  const float* __restrict__ A_log,
                                                  const float* __restrict__ Dp,
                                                  __hip_bfloat16* __restrict__ ybb) {
    __shared__ float sDU[CH][16][2];   // [l][dl][{dv, dv*xv}]
    __shared__ float sBC[CH][16][2];   // [l][n][{B, C}]
    __shared__ float sGW[CH][16][2];   // [l][dl][{g, D*xv*g}]
    const int b = blockIdx.y, dg = blockIdx.x;
    const int t = threadIdx.x;
    const int dl = t >> 4, n = t & 15;
    const int d = dg * 16 + dl;
    const float a = -__expf(A_log[d * DSTATE + n]);
    const int srow = t >> 4, scol = t & 15;
    const int sd = dg * 16 + scol;
    const float Dstage = Dp[sd];
    const float cb = conv_b[sd];
    const float w0 = conv_w[sd * 4 + 0];
    const float w1 = conv_w[sd * 4 + 1];
    const float w2 = conv_w[sd * 4 + 2];
    const float w3 = conv_w[sd * 4 + 3];
    const float* xbase = xz + (size_t)(b * SEQL) * 4096 + sd;   // col sd, rows of batch b

    float h = 0.f;
    for (int c = 0; c < NCHUNK; ++c) {
        const int rowbase = b * SEQL + c * CH;
        __syncthreads();   // protect LDS reuse across chunks
        #pragma unroll
        for (int i = 0; i < 4; ++i) {
            const int row = rowbase + i * 16 + srow;
            const int l = row & (SEQL - 1);
            const float dv = delta[(size_t)row * DINNER + sd];
            // inline conv + SiLU (identical order to the old conv kernel)
            float acc = cb;
            if (l >= 3) acc += w0 * xbase[(size_t)(l - 3) * 4096];
            if (l >= 2) acc += w1 * xbase[(size_t)(l - 2) * 4096];
            if (l >= 1) acc += w2 * xbase[(size_t)(l - 1) * 4096];
            acc += w3 * xbase[(size_t)l * 4096];
            const float xv = acc / (1.f + __expf(-acc));
            const float r  = xz[(size_t)row * 4096 + DINNER + sd];
            const float g = r / (1.f + __expf(-r));
            const int lr_ = i * 16 + srow;
            sDU[lr_][scol][0] = dv;
            sDU[lr_][scol][1] = dv * xv;
            sGW[lr_][scol][0] = g;
            sGW[lr_][scol][1] = Dstage * xv * g;
            sBC[lr_][scol][0] = xdbl[row * 128 + 64 + scol];
            sBC[lr_][scol][1] = xdbl[row * 128 + 80 + scol];
        }
        __syncthreads();
        #pragma unroll 16
        for (int l = 0; l < CH; ++l) {
            const float e = __expf(sDU[l][dl][0] * a);
            h = e * h + sDU[l][dl][1] * sBC[l][n][0];
            float pr = row_reduce16(h * sBC[l][n][1]);
            if (n == 0) {
                const float y = pr * sGW[l][dl][0] + sGW[l][dl][1];
                ybb[(size_t)(rowbase + l) * DINNER + d] = __float2bfloat16(y);
            }
        }
    }
}

// ---------------------------------------------------------------------------
// LayerNorm over last dim (1024), fused 4-way split-K reduce of out_proj
// partials. block per row, 256 threads x 4 elems.
// ---------------------------------------------------------------------------
__global__ __launch_bounds__(256) void ln_kernel(const float* __restrict__ opart,
                                                 const float* __restrict__ lw,
                                                 const float* __restrict__ lb,
                                                 float* __restrict__ out) {
    __shared__ float red[8];
    const int row = blockIdx.x;
    const int t = threadIdx.x;
    float v[4];
    float s = 0.f, s2 = 0.f;
    #pragma unroll
    for (int i = 0; i < 4; ++i) {
        const int c = t + 256 * i;
        float acc = 0.f;
        #pragma unroll
        for (int z = 0; z < 4; ++z)
            acc += opart[(size_t)z * (1024 * 1024) + (size_t)row * OUTC + c];
        v[i] = acc;
        s += acc;
        s2 += acc * acc;
    }
    #pragma unroll
    for (int o = 32; o; o >>= 1) {
        s += __shfl_down(s, o);
        s2 += __shfl_down(s2, o);
    }
    const int wid = t >> 6;
    if ((t & 63) == 0) { red[wid] = s; red[4 + wid] = s2; }
    __syncthreads();
    if (t == 0) {
        float ts = red[0] + red[1] + red[2] + red[3];
        float ts2 = red[4] + red[5] + red[6] + red[7];
        float mu = ts * (1.f / OUTC);
        float var = ts2 * (1.f / OUTC) - mu * mu;
        red[0] = mu;
        red[1] = rsqrtf(var + 1e-5f);
    }
    __syncthreads();
    const float mu = red[0], rs = red[1];
    #pragma unroll
    for (int i = 0; i < 4; ++i) {
        const int c = t + 256 * i;
        out[(size_t)row * OUTC + c] = (v[i] - mu) * rs * lw[c] + lb[c];
    }
}

// ---------------------------------------------------------------------------
extern "C" void kernel_launch(void* const* d_in, const int* in_sizes, int n_in,
                              void* d_out, int out_size, void* d_ws, size_t ws_size,
                              hipStream_t stream) {
    const float* x1        = (const float*)d_in[0];   // (1024,1024)
    const float* in_proj_w = (const float*)d_in[1];   // (4096,1024)
    const float* conv_w    = (const float*)d_in[2];   // (2048,1,4)
    const float* conv_b    = (const float*)d_in[3];   // (2048,)
    const float* x_proj_w  = (const float*)d_in[4];   // (96,2048)
    const float* dt_proj_w = (const float*)d_in[5];   // (2048,64)
    const float* dt_proj_b = (const float*)d_in[6];   // (2048,)
    const float* A_log     = (const float*)d_in[7];   // (2048,16)
    const float* Dp        = (const float*)d_in[8];   // (2048,)
    const float* out_proj_w= (const float*)d_in[9];   // (1024,2048)
    const float* ln_w      = (const float*)d_in[10];  // (1024,)
    const float* ln_b      = (const float*)d_in[11];  // (1024,)
    float* out = (float*)d_out;

    // workspace carve-up
    char* p = (char*)d_ws;
    __hip_bfloat16* xa    = (__hip_bfloat16*)p; p += (size_t)1024 * 1024 * 2;  // 2 MB
    __hip_bfloat16* wb1   = (__hip_bfloat16*)p; p += (size_t)4096 * 1024 * 2;  // 8 MB
    __hip_bfloat16* wpb   = (__hip_bfloat16*)p; p += (size_t)128 * 2048 * 2;   // 0.5 MB
    __hip_bfloat16* wob   = (__hip_bfloat16*)p; p += (size_t)1024 * 2048 * 2;  // 4 MB
    __hip_bfloat16* wdb   = (__hip_bfloat16*)p; p += (size_t)2048 * 64 * 2;    // 0.25 MB
    __hip_bfloat16* ybb   = (__hip_bfloat16*)p; p += (size_t)1024 * 2048 * 2;  // 4 MB
    __hip_bfloat16* xdblb = (__hip_bfloat16*)p; p += (size_t)1024 * 128 * 2;   // 0.25 MB
    float* xz    = (float*)p; p += (size_t)1024 * 4096 * 4;                    // 16 MB
    float* xdbl  = (float*)p; p += (size_t)1024 * 128 * 4;                     // 0.5 MB
    float* xpart = (float*)p; p += (size_t)XPZ * 1024 * 128 * 4;               // 8 MB
    float* delta = (float*)p; p += (size_t)1024 * 2048 * 4;                    // 8 MB
    // out_proj partials (16 MB) alias xz: scan_fused (last reader of xz)
    // precedes out_proj in stream order.
    float* opart = xz;

    // 0. fused bf16 casts
    cast_all_kernel<<<(R4 + 255) / 256, 256, 0, stream>>>(x1, in_proj_w, out_proj_w,
                                                          x_proj_w, dt_proj_w,
                                                          xa, wb1, wob, wpb, wdb);
    // 1. in_proj: xz = xa @ wb1^T   (1024 x 4096, K=1024)
    gemm_mfma<<<dim3(32, 8, 1), 256, 0, stream>>>(xa, wb1, xz,
                                                  NROWS, 2 * DINNER, DMODEL, DMODEL, DMODEL);
    // 2. x_proj with inline conv+SiLU: xpart[z] (1024 x 128, K-slices of 128 d)
    xproj_conv<<<dim3(XPZ, 8), 256, 0, stream>>>(xz, conv_w, conv_b, wpb, xpart);
    // 3. reduce partials -> xdbl fp32 + xdblb bf16
    xdbl_reduce_kernel<<<(1024 * 128) / 256, 256, 0, stream>>>(xpart, xdbl, xdblb);
    // 4. dt_proj + softplus -> delta (MFMA, K=64)
    gemm_dtsp<<<dim3(16, 8), 256, 0, stream>>>(xdblb, wdb, dt_proj_b, delta);
    // 5. single-pass scan (inline conv for xv) + gate -> ybb (bf16)
    scan_fused<<<dim3(DINNER / 16, BATCH), 256, 0, stream>>>(
        delta, xz, conv_w, conv_b, xdbl, A_log, Dp, ybb);
    // 6. out_proj partials: opart[z] = ybb @ wob^T (1024 x 1024, K=2048, split 4)
    gemm_mfma<<<dim3(8, 8, 4), 256, 0, stream>>>(ybb, wob, opart,
                                                 NROWS, OUTC, DINNER, DINNER, DINNER);
    // 7. LayerNorm (+ split-K reduce) -> out
    ln_kernel<<<NROWS, 256, 0, stream>>>(opart, ln_w, ln_b, out);
}

// Round 5
// 227.608 us; speedup vs baseline: 2.5351x; 1.0426x over previous
//
#include <hip/hip_runtime.h>
#include <hip/hip_bf16.h>
#include <math.h>

// Problem constants (from reference)
#define BATCH 4
#define SEQL 256          // L = C = 256
#define DMODEL 1024
#define DINNER 2048
#define DSTATE 16
#define OUTC 1024
#define NROWS (BATCH * SEQL)   // 1024
#define NCHUNK 4
#define CH 64             // SEQL / NCHUNK
#define XPZ 16            // x_proj split-K slices (each 128 d wide)

typedef __attribute__((ext_vector_type(8))) short bf16x8;  // 8 bf16 = 4 VGPRs
typedef __attribute__((ext_vector_type(4))) float f32x4;   // MFMA C/D

// ---------------------------------------------------------------------------
// bf16 MFMA GEMM, C = A @ B^T, split-K over blockIdx.z. 4-deep LDS pipeline,
// counted vmcnt (never 0 mid-loop), raw s_barrier. XCD-aware bijective
// swizzle of (bx,by): requires (gridDim.x*gridDim.y) % 8 == 0 (256 and 64).
// ---------------------------------------------------------------------------
__global__ __launch_bounds__(256) void gemm_mfma(const __hip_bfloat16* __restrict__ A,
                                                 const __hip_bfloat16* __restrict__ B,
                                                 float* __restrict__ C,
                                                 int M, int N, int K,
                                                 int lda, int ldb) {
    __shared__ __hip_bfloat16 As[4][128 * 32];
    __shared__ __hip_bfloat16 Bs[4][128 * 32];
    const int t  = threadIdx.x;
    const int w  = t >> 6;          // wave 0..3
    const int ln = t & 63;
    const int wm = w >> 1, wn = w & 1;
    const int q  = ln >> 4, lr = ln & 15;
    // XCD swizzle: blocks on the same XCD share a contiguous sid range
    const int id  = blockIdx.y * gridDim.x + blockIdx.x;
    const int nwg = gridDim.x * gridDim.y;
    const int sid = (id & 7) * (nwg >> 3) + (id >> 3);
    const int m0 = (sid / gridDim.x) * 128;
    const int n0 = (sid % gridDim.x) * 128;
    const int Kpart = K / gridDim.z;
    const int kbase = blockIdx.z * Kpart;

    f32x4 acc[4][4] = {};

    const __hip_bfloat16* Ag = A + (size_t)m0 * lda + kbase;
    const __hip_bfloat16* Bg = B + (size_t)n0 * ldb + kbase;

    auto stage = [&](int k0, int buf) {
        #pragma unroll
        for (int i = 0; i < 2; ++i) {
            const int c = (i * 4 + w) * 64 + ln;
            const int r = c >> 2, col = (c & 3) * 8;
            __builtin_amdgcn_global_load_lds(
                (const __attribute__((address_space(1))) void*)(Ag + (size_t)r * lda + k0 + col),
                (__attribute__((address_space(3))) void*)(As[buf] + (i * 4 + w) * 64 * 8),
                16, 0, 0);
            __builtin_amdgcn_global_load_lds(
                (const __attribute__((address_space(1))) void*)(Bg + (size_t)r * ldb + k0 + col),
                (__attribute__((address_space(3))) void*)(Bs[buf] + (i * 4 + w) * 64 * 8),
                16, 0, 0);
        }
    };

    const int nk = Kpart / 32;
    for (int s = 0; s < 3 && s < nk; ++s) stage(s * 32, s);

    for (int kk = 0; kk < nk; ++kk) {
        const int last = (kk + 2 < nk - 1) ? (kk + 2) : (nk - 1);
        const int nf = last - kk;      // younger stages to keep in flight
        if (nf >= 2)      asm volatile("s_waitcnt vmcnt(8)" ::: "memory");
        else if (nf == 1) asm volatile("s_waitcnt vmcnt(4)" ::: "memory");
        else              asm volatile("s_waitcnt vmcnt(0)" ::: "memory");
        __builtin_amdgcn_s_barrier();
        if (kk + 3 < nk) stage((kk + 3) * 32, (kk + 3) & 3);

        const int buf = kk & 3;
        bf16x8 af[4], bfr[4];
        #pragma unroll
        for (int i = 0; i < 4; ++i)
            af[i] = *(const bf16x8*)(As[buf] + (wm * 64 + i * 16 + lr) * 32 + q * 8);
        #pragma unroll
        for (int j = 0; j < 4; ++j)
            bfr[j] = *(const bf16x8*)(Bs[buf] + (wn * 64 + j * 16 + lr) * 32 + q * 8);
        #pragma unroll
        for (int i = 0; i < 4; ++i)
            #pragma unroll
            for (int j = 0; j < 4; ++j)
                acc[i][j] = __builtin_amdgcn_mfma_f32_16x16x32_bf16(af[i], bfr[j], acc[i][j], 0, 0, 0);
    }
    float* Cz = C + (size_t)blockIdx.z * M * N;
    #pragma unroll
    for (int i = 0; i < 4; ++i) {
        const int mrow = m0 + wm * 64 + i * 16 + q * 4;
        #pragma unroll
        for (int j = 0; j < 4; ++j) {
            const int ncol = n0 + wn * 64 + j * 16 + lr;
            #pragma unroll
            for (int r = 0; r < 4; ++r)
                Cz[(size_t)(mrow + r) * N + ncol] = acc[i][j][r];
        }
    }
}

// ---------------------------------------------------------------------------
// x_proj with INLINE depthwise conv + SiLU for the A operand. (verified r3)
// Block = (z K-slice of 128 d, m-tile of 128 rows). B (wpb) staged async;
// A computed from xz (conv+silu) into LDS while B loads fly; one barrier.
// ---------------------------------------------------------------------------
__global__ __launch_bounds__(256) void xproj_conv(const float* __restrict__ xz,
                                                  const float* __restrict__ conv_w,
                                                  const float* __restrict__ conv_b,
                                                  const __hip_bfloat16* __restrict__ Wp,
                                                  float* __restrict__ xpart) {
    __shared__ __hip_bfloat16 As[4 * 4096];
    __shared__ __hip_bfloat16 Bs[4 * 4096];
    const int t  = threadIdx.x;
    const int w  = t >> 6;
    const int ln = t & 63;
    const int wm = w >> 1, wn = w & 1;
    const int q  = ln >> 4, lr = ln & 15;
    const int z  = blockIdx.x;            // K-slice (d range)
    const int m0 = blockIdx.y * 128;
    const int kbase = z * 128;

    const __hip_bfloat16* Bg = Wp + kbase;          // ldb = 2048, n0 = 0
    #pragma unroll
    for (int stg = 0; stg < 4; ++stg) {
        #pragma unroll
        for (int i = 0; i < 2; ++i) {
            const int c = (i * 4 + w) * 64 + ln;
            const int r = c >> 2, col = (c & 3) * 8;
            __builtin_amdgcn_global_load_lds(
                (const __attribute__((address_space(1))) void*)(Bg + (size_t)r * 2048 + stg * 32 + col),
                (__attribute__((address_space(3))) void*)(Bs + stg * 4096 + (i * 4 + w) * 512),
                16, 0, 0);
        }
    }

    {
        const int r  = t >> 1;            // 0..127
        const int dh = (t & 1) * 16;      // 0 or 16 within each 32-wide k-step
        const int gr = m0 + r;
        const int bb = gr >> 8, l = gr & 255;
        const float* xrow = xz + (size_t)bb * 256 * 4096;
        #pragma unroll
        for (int stg = 0; stg < 4; ++stg) {
            const int d0 = kbase + stg * 32 + dh;
            #pragma unroll
            for (int j = 0; j < 4; ++j) {
                const int d = d0 + j * 4;
                float4 t0 = {}, t1 = {}, t2 = {}, t3;
                if (l >= 3) t0 = *(const float4*)(xrow + (size_t)(l - 3) * 4096 + d);
                if (l >= 2) t1 = *(const float4*)(xrow + (size_t)(l - 2) * 4096 + d);
                if (l >= 1) t2 = *(const float4*)(xrow + (size_t)(l - 1) * 4096 + d);
                t3 = *(const float4*)(xrow + (size_t)l * 4096 + d);
                const float* p0 = (const float*)&t0;
                const float* p1 = (const float*)&t1;
                const float* p2 = (const float*)&t2;
                const float* p3 = (const float*)&t3;
                #pragma unroll
                for (int u = 0; u < 4; ++u) {
                    const int du = d + u;
                    const float4 wv = *(const float4*)(conv_w + (size_t)du * 4);
                    float acc = conv_b[du];
                    if (l >= 3) acc += wv.x * p0[u];
                    if (l >= 2) acc += wv.y * p1[u];
                    if (l >= 1) acc += wv.z * p2[u];
                    acc += wv.w * p3[u];
                    const float v = acc / (1.f + __expf(-acc));
                    As[stg * 4096 + r * 32 + dh + j * 4 + u] = __float2bfloat16(v);
                }
            }
        }
    }
    __syncthreads();   // drains B loads (vmcnt) + A ds_writes (lgkm) + barrier

    f32x4 acc[4][4] = {};
    #pragma unroll
    for (int kk = 0; kk < 4; ++kk) {
        const __hip_bfloat16* Ab = As + kk * 4096;
        const __hip_bfloat16* Bb = Bs + kk * 4096;
        bf16x8 af[4], bfr[4];
        #pragma unroll
        for (int i = 0; i < 4; ++i)
            af[i] = *(const bf16x8*)(Ab + (wm * 64 + i * 16 + lr) * 32 + q * 8);
        #pragma unroll
        for (int j = 0; j < 4; ++j)
            bfr[j] = *(const bf16x8*)(Bb + (wn * 64 + j * 16 + lr) * 32 + q * 8);
        #pragma unroll
        for (int i = 0; i < 4; ++i)
            #pragma unroll
            for (int j = 0; j < 4; ++j)
                acc[i][j] = __builtin_amdgcn_mfma_f32_16x16x32_bf16(af[i], bfr[j], acc[i][j], 0, 0, 0);
    }
    float* Cz = xpart + (size_t)z * (1024 * 128);
    #pragma unroll
    for (int i = 0; i < 4; ++i) {
        const int mrow = m0 + wm * 64 + i * 16 + q * 4;
        #pragma unroll
        for (int j = 0; j < 4; ++j) {
            const int ncol = wn * 64 + j * 16 + lr;
            #pragma unroll
            for (int r = 0; r < 4; ++r)
                Cz[(size_t)(mrow + r) * 128 + ncol] = acc[i][j][r];
        }
    }
}

// ---------------------------------------------------------------------------
// dt_proj as MFMA GEMM with fused bias + softplus epilogue. (K=64, 2 iters)
// ---------------------------------------------------------------------------
__global__ __launch_bounds__(256) void gemm_dtsp(const __hip_bfloat16* __restrict__ A,
                                                 const __hip_bfloat16* __restrict__ B,
                                                 const float* __restrict__ bd,
                                                 float* __restrict__ delta) {
    __shared__ __hip_bfloat16 As[2][128 * 32];
    __shared__ __hip_bfloat16 Bs[2][128 * 32];
    const int t  = threadIdx.x;
    const int w  = t >> 6;
    const int ln = t & 63;
    const int wm = w >> 1, wn = w & 1;
    const int q  = ln >> 4, lr = ln & 15;
    const int m0 = blockIdx.y * 128;
    const int n0 = blockIdx.x * 128;
    const int lda = 128, ldb = 64, N = 2048;

    f32x4 acc[4][4] = {};
    const __hip_bfloat16* Ag = A + (size_t)m0 * lda;
    const __hip_bfloat16* Bg = B + (size_t)n0 * ldb;

    auto stage = [&](int k0, int buf) {
        #pragma unroll
        for (int i = 0; i < 2; ++i) {
            const int c = (i * 4 + w) * 64 + ln;
            const int r = c >> 2, col = (c & 3) * 8;
            __builtin_amdgcn_global_load_lds(
                (const __attribute__((address_space(1))) void*)(Ag + (size_t)r * lda + k0 + col),
                (__attribute__((address_space(3))) void*)(As[buf] + (i * 4 + w) * 64 * 8),
                16, 0, 0);
            __builtin_amdgcn_global_load_lds(
                (const __attribute__((address_space(1))) void*)(Bg + (size_t)r * ldb + k0 + col),
                (__attribute__((address_space(3))) void*)(Bs[buf] + (i * 4 + w) * 64 * 8),
                16, 0, 0);
        }
    };

    stage(0, 0);
    stage(32, 1);
    #pragma unroll
    for (int kk = 0; kk < 2; ++kk) {
        if (kk == 0) asm volatile("s_waitcnt vmcnt(4)" ::: "memory");
        else         asm volatile("s_waitcnt vmcnt(0)" ::: "memory");
        __builtin_amdgcn_s_barrier();
        bf16x8 af[4], bfr[4];
        #pragma unroll
        for (int i = 0; i < 4; ++i)
            af[i] = *(const bf16x8*)(As[kk] + (wm * 64 + i * 16 + lr) * 32 + q * 8);
        #pragma unroll
        for (int j = 0; j < 4; ++j)
            bfr[j] = *(const bf16x8*)(Bs[kk] + (wn * 64 + j * 16 + lr) * 32 + q * 8);
        #pragma unroll
        for (int i = 0; i < 4; ++i)
            #pragma unroll
            for (int j = 0; j < 4; ++j)
                acc[i][j] = __builtin_amdgcn_mfma_f32_16x16x32_bf16(af[i], bfr[j], acc[i][j], 0, 0, 0);
    }
    #pragma unroll
    for (int i = 0; i < 4; ++i) {
        const int mrow = m0 + wm * 64 + i * 16 + q * 4;
        #pragma unroll
        for (int j = 0; j < 4; ++j) {
            const int ncol = n0 + wn * 64 + j * 16 + lr;
            const float bias = bd[ncol];
            #pragma unroll
            for (int r = 0; r < 4; ++r) {
                float v = acc[i][j][r] + bias;
                float sp = (v > 20.f) ? v : log1pf(__expf(v));
                delta[(size_t)(mrow + r) * N + ncol] = sp;
            }
        }
    }
}

// ---------------------------------------------------------------------------
// Reduce XPZ split-K partials of x_proj -> xdbl fp32 (1024x128) + xdblb bf16.
// ---------------------------------------------------------------------------
__global__ void xdbl_reduce_kernel(const float* __restrict__ part,
                                   float* __restrict__ xdbl,
                                   __hip_bfloat16* __restrict__ xdblb) {
    const int i = blockIdx.x * 256 + threadIdx.x;   // 1024*128
    float s = 0.f;
    #pragma unroll
    for (int z = 0; z < XPZ; ++z) s += part[(size_t)z * (1024 * 128) + i];
    xdbl[i] = s;
    xdblb[i] = __float2bfloat16(s);
}

// ---------------------------------------------------------------------------
// Fused fp32 -> bf16 casts, float4-vectorized (all regions are %4 sized).
// ---------------------------------------------------------------------------
#define R0 (1024 * 1024)
#define R1 (R0 + 4096 * 1024)
#define R2 (R1 + 2048 * 1024)
#define R3 (R2 + 128 * 2048)
#define R4 (R3 + 2048 * 64)

__device__ __forceinline__ ushort4 cvt4(float4 v) {
    __hip_bfloat16 h0 = __float2bfloat16(v.x);
    __hip_bfloat16 h1 = __float2bfloat16(v.y);
    __hip_bfloat16 h2 = __float2bfloat16(v.z);
    __hip_bfloat16 h3 = __float2bfloat16(v.w);
    ushort4 o;
    o.x = *reinterpret_cast<unsigned short*>(&h0);
    o.y = *reinterpret_cast<unsigned short*>(&h1);
    o.z = *reinterpret_cast<unsigned short*>(&h2);
    o.w = *reinterpret_cast<unsigned short*>(&h3);
    return o;
}

__global__ void cast_all_kernel(const float* __restrict__ x1,
                                const float* __restrict__ w_in,
                                const float* __restrict__ w_out,
                                const float* __restrict__ w_xp,
                                const float* __restrict__ w_dt,
                                __hip_bfloat16* __restrict__ xa,
                                __hip_bfloat16* __restrict__ wb1,
                                __hip_bfloat16* __restrict__ wob,
                                __hip_bfloat16* __restrict__ wpb,
                                __hip_bfloat16* __restrict__ wdb) {
    const int i = (blockIdx.x * 256 + threadIdx.x) * 4;
    if (i >= R4) return;
    if (i < R0) {
        *reinterpret_cast<ushort4*>(xa + i) = cvt4(*(const float4*)(x1 + i));
    } else if (i < R1) {
        int j = i - R0;
        *reinterpret_cast<ushort4*>(wb1 + j) = cvt4(*(const float4*)(w_in + j));
    } else if (i < R2) {
        int j = i - R1;
        *reinterpret_cast<ushort4*>(wob + j) = cvt4(*(const float4*)(w_out + j));
    } else if (i < R3) {
        int j = i - R2; int e = j >> 11;
        float4 v = (e < 96) ? *(const float4*)(w_xp + j) : float4{0.f, 0.f, 0.f, 0.f};
        *reinterpret_cast<ushort4*>(wpb + j) = cvt4(v);
    } else {
        int j = i - R3;
        *reinterpret_cast<ushort4*>(wdb + j) = cvt4(*(const float4*)(w_dt + j));
    }
}

// ---------------------------------------------------------------------------
// 16-lane row sum via DPP row_ror rotations (no DS ops).
// ---------------------------------------------------------------------------
__device__ __forceinline__ float row_reduce16(float x) {
    x += __int_as_float(__builtin_amdgcn_update_dpp(0, __float_as_int(x), 0x128, 0xF, 0xF, true));
    x += __int_as_float(__builtin_amdgcn_update_dpp(0, __float_as_int(x), 0x124, 0xF, 0xF, true));
    x += __int_as_float(__builtin_amdgcn_update_dpp(0, __float_as_int(x), 0x122, 0xF, 0xF, true));
    x += __int_as_float(__builtin_amdgcn_update_dpp(0, __float_as_int(x), 0x121, 0xF, 0xF, true));
    return x;
}

// ---------------------------------------------------------------------------
// Chunk-parallel scan, phase A: per-chunk local recurrence with INLINE conv.
// Grid (128, B, 3): chunk 3's carry is never consumed -> not computed.
// ---------------------------------------------------------------------------
__global__ __launch_bounds__(256) void scan_carry_kernel(const float* __restrict__ delta,
                                                         const float* __restrict__ xz,
                                                         const float* __restrict__ conv_w,
                                                         const float* __restrict__ conv_b,
                                                         const float* __restrict__ xdbl,
                                                         const float* __restrict__ A_log,
                                                         float* __restrict__ carryL,
                                                         float* __restrict__ carryP) {
    __shared__ float sDU[CH][16][2];   // [l][dl][{dv, dv*xv}]
    __shared__ float sB[CH][16];       // [l][n]
    const int b = blockIdx.y, c = blockIdx.z, dg = blockIdx.x;
    const int t = threadIdx.x;
    const int dl = t >> 4, n = t & 15;
    const int d = dg * 16 + dl;
    const float a = -__expf(A_log[d * DSTATE + n]);
    const int srow = t >> 4, scol = t & 15;
    const int sd = dg * 16 + scol;
    const float cb = conv_b[sd];
    const float w0 = conv_w[sd * 4 + 0];
    const float w1 = conv_w[sd * 4 + 1];
    const float w2 = conv_w[sd * 4 + 2];
    const float w3 = conv_w[sd * 4 + 3];
    const float* xbase = xz + (size_t)(b * SEQL) * 4096 + sd;
    const int rowbase = b * SEQL + c * CH;
    #pragma unroll
    for (int i = 0; i < 4; ++i) {
        const int row = rowbase + i * 16 + srow;
        const int l = row & (SEQL - 1);
        const float dv = delta[(size_t)row * DINNER + sd];
        float acc = cb;
        if (l >= 3) acc += w0 * xbase[(size_t)(l - 3) * 4096];
        if (l >= 2) acc += w1 * xbase[(size_t)(l - 2) * 4096];
        if (l >= 1) acc += w2 * xbase[(size_t)(l - 1) * 4096];
        acc += w3 * xbase[(size_t)l * 4096];
        const float xv = acc / (1.f + __expf(-acc));
        sDU[i * 16 + srow][scol][0] = dv;
        sDU[i * 16 + srow][scol][1] = dv * xv;
        sB[i * 16 + srow][scol] = xdbl[row * 128 + 64 + scol];
    }
    __syncthreads();
    float h = 0.f, P = 1.f;
    #pragma unroll 16
    for (int l = 0; l < CH; ++l) {
        const float e = __expf(sDU[l][dl][0] * a);
        h = e * h + sDU[l][dl][1] * sB[l][n];
        P *= e;
    }
    const size_t ci = (((size_t)(b * NCHUNK + c)) * DINNER + d) * DSTATE + n;
    carryL[ci] = h;
    carryP[ci] = P;
}

// ---------------------------------------------------------------------------
// Chunk-parallel scan, phase B: combine carries (h = P_j h + L_j, j < c) then
// run the 64-step scan with INLINE conv, +D*xs, *silu(res), bf16 out.
// ---------------------------------------------------------------------------
__global__ __launch_bounds__(256) void scan_apply_kernel(const float* __restrict__ delta,
                                                         const float* __restrict__ xz,
                                                         const float* __restrict__ conv_w,
                                                         const float* __restrict__ conv_b,
                                                         const float* __restrict__ xdbl,
                                                         const float* __restrict__ A_log,
                                                         const float* __restrict__ Dp,
                                                         const float* __restrict__ carryL,
                                                         const float* __restrict__ carryP,
                                                         __hip_bfloat16* __restrict__ ybb) {
    __shared__ float sDU[CH][16][2];   // [l][dl][{dv, dv*xv}]
    __shared__ float sBC[CH][16][2];   // [l][n][{B, C}]
    __shared__ float sGW[CH][16][2];   // [l][dl][{g, D*xv*g}]
    const int b = blockIdx.y, c = blockIdx.z, dg = blockIdx.x;
    const int t = threadIdx.x;
    const int dl = t >> 4, n = t & 15;
    const int d = dg * 16 + dl;
    const float a = -__expf(A_log[d * DSTATE + n]);
    const int srow = t >> 4, scol = t & 15;
    const int sd = dg * 16 + scol;
    const float Dstage = Dp[sd];
    const float cb = conv_b[sd];
    const float w0 = conv_w[sd * 4 + 0];
    const float w1 = conv_w[sd * 4 + 1];
    const float w2 = conv_w[sd * 4 + 2];
    const float w3 = conv_w[sd * 4 + 3];
    const float* xbase = xz + (size_t)(b * SEQL) * 4096 + sd;
    const int rowbase = b * SEQL + c * CH;
    #pragma unroll
    for (int i = 0; i < 4; ++i) {
        const int row = rowbase + i * 16 + srow;
        const int l = row & (SEQL - 1);
        const float dv = delta[(size_t)row * DINNER + sd];
        float acc = cb;
        if (l >= 3) acc += w0 * xbase[(size_t)(l - 3) * 4096];
        if (l >= 2) acc += w1 * xbase[(size_t)(l - 2) * 4096];
        if (l >= 1) acc += w2 * xbase[(size_t)(l - 1) * 4096];
        acc += w3 * xbase[(size_t)l * 4096];
        const float xv = acc / (1.f + __expf(-acc));
        const float r  = xz[(size_t)row * 4096 + DINNER + sd];
        const float g = r / (1.f + __expf(-r));
        const int lr_ = i * 16 + srow;
        sDU[lr_][scol][0] = dv;
        sDU[lr_][scol][1] = dv * xv;
        sGW[lr_][scol][0] = g;
        sGW[lr_][scol][1] = Dstage * xv * g;
        sBC[lr_][scol][0] = xdbl[row * 128 + 64 + scol];
        sBC[lr_][scol][1] = xdbl[row * 128 + 80 + scol];
    }
    __syncthreads();
    float h = 0.f;
    for (int j = 0; j < c; ++j) {
        const size_t ci = (((size_t)(b * NCHUNK + j)) * DINNER + d) * DSTATE + n;
        h = carryP[ci] * h + carryL[ci];
    }
    #pragma unroll 16
    for (int l = 0; l < CH; ++l) {
        const float e = __expf(sDU[l][dl][0] * a);
        h = e * h + sDU[l][dl][1] * sBC[l][n][0];
        float pr = row_reduce16(h * sBC[l][n][1]);
        if (n == 0) {
            const float y = pr * sGW[l][dl][0] + sGW[l][dl][1];
            ybb[(size_t)(rowbase + l) * DINNER + d] = __float2bfloat16(y);
        }
    }
}

// ---------------------------------------------------------------------------
// LayerNorm over last dim (1024), fused 4-way split-K reduce of out_proj
// partials. block per row, 256 threads x 4 elems.
// ---------------------------------------------------------------------------
__global__ __launch_bounds__(256) void ln_kernel(const float* __restrict__ opart,
                                                 const float* __restrict__ lw,
                                                 const float* __restrict__ lb,
                                                 float* __restrict__ out) {
    __shared__ float red[8];
    const int row = blockIdx.x;
    const int t = threadIdx.x;
    float v[4];
    float s = 0.f, s2 = 0.f;
    #pragma unroll
    for (int i = 0; i < 4; ++i) {
        const int c = t + 256 * i;
        float acc = 0.f;
        #pragma unroll
        for (int z = 0; z < 4; ++z)
            acc += opart[(size_t)z * (1024 * 1024) + (size_t)row * OUTC + c];
        v[i] = acc;
        s += acc;
        s2 += acc * acc;
    }
    #pragma unroll
    for (int o = 32; o; o >>= 1) {
        s += __shfl_down(s, o);
        s2 += __shfl_down(s2, o);
    }
    const int wid = t >> 6;
    if ((t & 63) == 0) { red[wid] = s; red[4 + wid] = s2; }
    __syncthreads();
    if (t == 0) {
        float ts = red[0] + red[1] + red[2] + red[3];
        float ts2 = red[4] + red[5] + red[6] + red[7];
        float mu = ts * (1.f / OUTC);
        float var = ts2 * (1.f / OUTC) - mu * mu;
        red[0] = mu;
        red[1] = rsqrtf(var + 1e-5f);
    }
    __syncthreads();
    const float mu = red[0], rs = red[1];
    #pragma unroll
    for (int i = 0; i < 4; ++i) {
        const int c = t + 256 * i;
        out[(size_t)row * OUTC + c] = (v[i] - mu) * rs * lw[c] + lb[c];
    }
}

// ---------------------------------------------------------------------------
extern "C" void kernel_launch(void* const* d_in, const int* in_sizes, int n_in,
                              void* d_out, int out_size, void* d_ws, size_t ws_size,
                              hipStream_t stream) {
    const float* x1        = (const float*)d_in[0];   // (1024,1024)
    const float* in_proj_w = (const float*)d_in[1];   // (4096,1024)
    const float* conv_w    = (const float*)d_in[2];   // (2048,1,4)
    const float* conv_b    = (const float*)d_in[3];   // (2048,)
    const float* x_proj_w  = (const float*)d_in[4];   // (96,2048)
    const float* dt_proj_w = (const float*)d_in[5];   // (2048,64)
    const float* dt_proj_b = (const float*)d_in[6];   // (2048,)
    const float* A_log     = (const float*)d_in[7];   // (2048,16)
    const float* Dp        = (const float*)d_in[8];   // (2048,)
    const float* out_proj_w= (const float*)d_in[9];   // (1024,2048)
    const float* ln_w      = (const float*)d_in[10];  // (1024,)
    const float* ln_b      = (const float*)d_in[11];  // (1024,)
    float* out = (float*)d_out;

    // workspace carve-up
    char* p = (char*)d_ws;
    __hip_bfloat16* xa    = (__hip_bfloat16*)p; p += (size_t)1024 * 1024 * 2;  // 2 MB
    __hip_bfloat16* wb1   = (__hip_bfloat16*)p; p += (size_t)4096 * 1024 * 2;  // 8 MB
    __hip_bfloat16* wpb   = (__hip_bfloat16*)p; p += (size_t)128 * 2048 * 2;   // 0.5 MB
    __hip_bfloat16* wob   = (__hip_bfloat16*)p; p += (size_t)1024 * 2048 * 2;  // 4 MB
    __hip_bfloat16* wdb   = (__hip_bfloat16*)p; p += (size_t)2048 * 64 * 2;    // 0.25 MB
    __hip_bfloat16* ybb   = (__hip_bfloat16*)p; p += (size_t)1024 * 2048 * 2;  // 4 MB
    __hip_bfloat16* xdblb = (__hip_bfloat16*)p; p += (size_t)1024 * 128 * 2;   // 0.25 MB
    float* xz    = (float*)p; p += (size_t)1024 * 4096 * 4;                    // 16 MB
    float* xdbl  = (float*)p; p += (size_t)1024 * 128 * 4;                     // 0.5 MB
    float* xpart = (float*)p; p += (size_t)XPZ * 1024 * 128 * 4;               // 8 MB
    float* delta = (float*)p; p += (size_t)1024 * 2048 * 4;                    // 8 MB
    float* carryL = (float*)p; p += (size_t)BATCH * NCHUNK * DINNER * DSTATE * 4; // 2 MB
    float* carryP = (float*)p; p += (size_t)BATCH * NCHUNK * DINNER * DSTATE * 4; // 2 MB
    // out_proj partials (16 MB) alias xz: scan B (last reader of xz) precedes
    // out_proj in stream order.
    float* opart = xz;

    // 0. fused bf16 casts (float4-vectorized)
    cast_all_kernel<<<(R4 / 4 + 255) / 256, 256, 0, stream>>>(x1, in_proj_w, out_proj_w,
                                                              x_proj_w, dt_proj_w,
                                                              xa, wb1, wob, wpb, wdb);
    // 1. in_proj: xz = xa @ wb1^T   (1024 x 4096, K=1024)
    gemm_mfma<<<dim3(32, 8, 1), 256, 0, stream>>>(xa, wb1, xz,
                                                  NROWS, 2 * DINNER, DMODEL, DMODEL, DMODEL);
    // 2. x_proj with inline conv+SiLU: xpart[z] (1024 x 128, K-slices of 128 d)
    xproj_conv<<<dim3(XPZ, 8), 256, 0, stream>>>(xz, conv_w, conv_b, wpb, xpart);
    // 3. reduce partials -> xdbl fp32 + xdblb bf16
    xdbl_reduce_kernel<<<(1024 * 128) / 256, 256, 0, stream>>>(xpart, xdbl, xdblb);
    // 4. dt_proj + softplus -> delta (MFMA, K=64)
    gemm_dtsp<<<dim3(16, 8), 256, 0, stream>>>(xdblb, wdb, dt_proj_b, delta);
    // 5a. scan phase A: per-chunk carries (chunks 0..2 only; 1536 blocks)
    scan_carry_kernel<<<dim3(DINNER / 16, BATCH, NCHUNK - 1), 256, 0, stream>>>(
        delta, xz, conv_w, conv_b, xdbl, A_log, carryL, carryP);
    // 5b. scan phase B: combine + apply + gate -> ybb (bf16) (2048 blocks)
    scan_apply_kernel<<<dim3(DINNER / 16, BATCH, NCHUNK), 256, 0, stream>>>(
        delta, xz, conv_w, conv_b, xdbl, A_log, Dp, carryL, carryP, ybb);
    // 6. out_proj partials: opart[z] = ybb @ wob^T (1024 x 1024, K=2048, split 4)
    gemm_mfma<<<dim3(8, 8, 4), 256, 0, stream>>>(ybb, wob, opart,
                                                 NROWS, OUTC, DINNER, DINNER, DINNER);
    // 7. LayerNorm (+ split-K reduce) -> out
    ln_kernel<<<NROWS, 256, 0, stream>>>(opart, ln_w, ln_b, out);
}

// Round 6
// 209.299 us; speedup vs baseline: 2.7569x; 1.0875x over previous
//
#include <hip/hip_runtime.h>
#include <hip/hip_bf16.h>
#include <math.h>

// Problem constants (from reference)
#define BATCH 4
#define SEQL 256          // L = C = 256
#define DMODEL 1024
#define DINNER 2048
#define DSTATE 16
#define OUTC 1024
#define NROWS (BATCH * SEQL)   // 1024
#define NCHUNK 4
#define CH 64             // SEQL / NCHUNK
#define XPZ 16            // x_proj split-K slices

typedef __attribute__((ext_vector_type(8))) short bf16x8;  // 8 bf16 = 4 VGPRs
typedef __attribute__((ext_vector_type(4))) float f32x4;   // MFMA C/D

// ---------------------------------------------------------------------------
// bf16 MFMA GEMM, C = A @ B^T, 128x64 tile (M x N), split-K over blockIdx.z.
// Half-size B panel doubles the grid vs 128x128 -> 2 blocks/CU (8 waves/CU)
// on every call site: cross-block TLP hides load latency that the 1-block/CU
// 128x128 variant could not (r0 null). 4-deep LDS pipeline (48 KB), counted
// vmcnt (3 loads/stage/wave: vmcnt 6/3/0), raw s_barrier.
// Wave layout: 2x2 waves, each owns 64x32 (acc[4][2]).
// ---------------------------------------------------------------------------
__global__ __launch_bounds__(256) void gemm_n64(const __hip_bfloat16* __restrict__ A,
                                                const __hip_bfloat16* __restrict__ B,
                                                float* __restrict__ C,
                                                int M, int N, int K,
                                                int lda, int ldb) {
    __shared__ __hip_bfloat16 As[4][128 * 32];   // 32 KB
    __shared__ __hip_bfloat16 Bs[4][64 * 32];    // 16 KB
    const int t  = threadIdx.x;
    const int w  = t >> 6;          // wave 0..3
    const int ln = t & 63;
    const int wm = w >> 1, wn = w & 1;
    const int q  = ln >> 4, lr = ln & 15;
    const int m0 = blockIdx.y * 128;
    const int n0 = blockIdx.x * 64;
    const int Kpart = K / gridDim.z;
    const int kbase = blockIdx.z * Kpart;

    f32x4 acc[4][2] = {};

    const __hip_bfloat16* Ag = A + (size_t)m0 * lda + kbase;
    const __hip_bfloat16* Bg = B + (size_t)n0 * ldb + kbase;

    auto stage = [&](int k0, int buf) {
        #pragma unroll
        for (int i = 0; i < 2; ++i) {            // A: 8 KB (2 loads/wave)
            const int c = (i * 4 + w) * 64 + ln;
            const int r = c >> 2, col = (c & 3) * 8;
            __builtin_amdgcn_global_load_lds(
                (const __attribute__((address_space(1))) void*)(Ag + (size_t)r * lda + k0 + col),
                (__attribute__((address_space(3))) void*)(As[buf] + (i * 4 + w) * 512),
                16, 0, 0);
        }
        {                                        // B: 4 KB (1 load/wave)
            const int c = w * 64 + ln;
            const int r = c >> 2, col = (c & 3) * 8;
            __builtin_amdgcn_global_load_lds(
                (const __attribute__((address_space(1))) void*)(Bg + (size_t)r * ldb + k0 + col),
                (__attribute__((address_space(3))) void*)(Bs[buf] + w * 512),
                16, 0, 0);
        }
    };

    const int nk = Kpart / 32;
    for (int s = 0; s < 3 && s < nk; ++s) stage(s * 32, s);

    for (int kk = 0; kk < nk; ++kk) {
        const int last = (kk + 2 < nk - 1) ? (kk + 2) : (nk - 1);
        const int nf = last - kk;      // younger stages in flight (3 loads each)
        if (nf >= 2)      asm volatile("s_waitcnt vmcnt(6)" ::: "memory");
        else if (nf == 1) asm volatile("s_waitcnt vmcnt(3)" ::: "memory");
        else              asm volatile("s_waitcnt vmcnt(0)" ::: "memory");
        __builtin_amdgcn_s_barrier();
        if (kk + 3 < nk) stage((kk + 3) * 32, (kk + 3) & 3);

        const int buf = kk & 3;
        bf16x8 af[4], bfr[2];
        #pragma unroll
        for (int i = 0; i < 4; ++i)
            af[i] = *(const bf16x8*)(As[buf] + (wm * 64 + i * 16 + lr) * 32 + q * 8);
        #pragma unroll
        for (int j = 0; j < 2; ++j)
            bfr[j] = *(const bf16x8*)(Bs[buf] + (wn * 32 + j * 16 + lr) * 32 + q * 8);
        #pragma unroll
        for (int i = 0; i < 4; ++i)
            #pragma unroll
            for (int j = 0; j < 2; ++j)
                acc[i][j] = __builtin_amdgcn_mfma_f32_16x16x32_bf16(af[i], bfr[j], acc[i][j], 0, 0, 0);
    }
    float* Cz = C + (size_t)blockIdx.z * M * N;
    #pragma unroll
    for (int i = 0; i < 4; ++i) {
        const int mrow = m0 + wm * 64 + i * 16 + q * 4;
        #pragma unroll
        for (int j = 0; j < 2; ++j) {
            const int ncol = n0 + wn * 32 + j * 16 + lr;
            #pragma unroll
            for (int r = 0; r < 4; ++r)
                Cz[(size_t)(mrow + r) * N + ncol] = acc[i][j][r];
        }
    }
}

// ---------------------------------------------------------------------------
// dt_proj as MFMA GEMM with fused bias + softplus epilogue. (K=64, 2 iters)
// ---------------------------------------------------------------------------
__global__ __launch_bounds__(256) void gemm_dtsp(const __hip_bfloat16* __restrict__ A,
                                                 const __hip_bfloat16* __restrict__ B,
                                                 const float* __restrict__ bd,
                                                 float* __restrict__ delta) {
    __shared__ __hip_bfloat16 As[2][128 * 32];
    __shared__ __hip_bfloat16 Bs[2][128 * 32];
    const int t  = threadIdx.x;
    const int w  = t >> 6;
    const int ln = t & 63;
    const int wm = w >> 1, wn = w & 1;
    const int q  = ln >> 4, lr = ln & 15;
    const int m0 = blockIdx.y * 128;
    const int n0 = blockIdx.x * 128;
    const int lda = 128, ldb = 64, N = 2048;

    f32x4 acc[4][4] = {};
    const __hip_bfloat16* Ag = A + (size_t)m0 * lda;
    const __hip_bfloat16* Bg = B + (size_t)n0 * ldb;

    auto stage = [&](int k0, int buf) {
        #pragma unroll
        for (int i = 0; i < 2; ++i) {
            const int c = (i * 4 + w) * 64 + ln;
            const int r = c >> 2, col = (c & 3) * 8;
            __builtin_amdgcn_global_load_lds(
                (const __attribute__((address_space(1))) void*)(Ag + (size_t)r * lda + k0 + col),
                (__attribute__((address_space(3))) void*)(As[buf] + (i * 4 + w) * 64 * 8),
                16, 0, 0);
            __builtin_amdgcn_global_load_lds(
                (const __attribute__((address_space(1))) void*)(Bg + (size_t)r * ldb + k0 + col),
                (__attribute__((address_space(3))) void*)(Bs[buf] + (i * 4 + w) * 64 * 8),
                16, 0, 0);
        }
    };

    stage(0, 0);
    stage(32, 1);
    #pragma unroll
    for (int kk = 0; kk < 2; ++kk) {
        if (kk == 0) asm volatile("s_waitcnt vmcnt(4)" ::: "memory");
        else         asm volatile("s_waitcnt vmcnt(0)" ::: "memory");
        __builtin_amdgcn_s_barrier();
        bf16x8 af[4], bfr[4];
        #pragma unroll
        for (int i = 0; i < 4; ++i)
            af[i] = *(const bf16x8*)(As[kk] + (wm * 64 + i * 16 + lr) * 32 + q * 8);
        #pragma unroll
        for (int j = 0; j < 4; ++j)
            bfr[j] = *(const bf16x8*)(Bs[kk] + (wn * 64 + j * 16 + lr) * 32 + q * 8);
        #pragma unroll
        for (int i = 0; i < 4; ++i)
            #pragma unroll
            for (int j = 0; j < 4; ++j)
                acc[i][j] = __builtin_amdgcn_mfma_f32_16x16x32_bf16(af[i], bfr[j], acc[i][j], 0, 0, 0);
    }
    #pragma unroll
    for (int i = 0; i < 4; ++i) {
        const int mrow = m0 + wm * 64 + i * 16 + q * 4;
        #pragma unroll
        for (int j = 0; j < 4; ++j) {
            const int ncol = n0 + wn * 64 + j * 16 + lr;
            const float bias = bd[ncol];
            #pragma unroll
            for (int r = 0; r < 4; ++r) {
                float v = acc[i][j][r] + bias;
                float sp = (v > 20.f) ? v : log1pf(__expf(v));
                delta[(size_t)(mrow + r) * N + ncol] = sp;
            }
        }
    }
}

// ---------------------------------------------------------------------------
// Reduce XPZ split-K partials of x_proj -> xdbl fp32 (1024x128) + xdblb bf16.
// ---------------------------------------------------------------------------
__global__ void xdbl_reduce_kernel(const float* __restrict__ part,
                                   float* __restrict__ xdbl,
                                   __hip_bfloat16* __restrict__ xdblb) {
    const int i = blockIdx.x * 256 + threadIdx.x;   // 1024*128
    float s = 0.f;
    #pragma unroll
    for (int z = 0; z < XPZ; ++z) s += part[(size_t)z * (1024 * 128) + i];
    xdbl[i] = s;
    xdblb[i] = __float2bfloat16(s);
}

// ---------------------------------------------------------------------------
// Fused fp32 -> bf16 casts, float4-vectorized (all regions are %4 sized).
// ---------------------------------------------------------------------------
#define R0 (1024 * 1024)
#define R1 (R0 + 4096 * 1024)
#define R2 (R1 + 2048 * 1024)
#define R3 (R2 + 128 * 2048)
#define R4 (R3 + 2048 * 64)

__device__ __forceinline__ ushort4 cvt4(float4 v) {
    __hip_bfloat16 h0 = __float2bfloat16(v.x);
    __hip_bfloat16 h1 = __float2bfloat16(v.y);
    __hip_bfloat16 h2 = __float2bfloat16(v.z);
    __hip_bfloat16 h3 = __float2bfloat16(v.w);
    ushort4 o;
    o.x = *reinterpret_cast<unsigned short*>(&h0);
    o.y = *reinterpret_cast<unsigned short*>(&h1);
    o.z = *reinterpret_cast<unsigned short*>(&h2);
    o.w = *reinterpret_cast<unsigned short*>(&h3);
    return o;
}

__global__ void cast_all_kernel(const float* __restrict__ x1,
                                const float* __restrict__ w_in,
                                const float* __restrict__ w_out,
                                const float* __restrict__ w_xp,
                                const float* __restrict__ w_dt,
                                __hip_bfloat16* __restrict__ xa,
                                __hip_bfloat16* __restrict__ wb1,
                                __hip_bfloat16* __restrict__ wob,
                                __hip_bfloat16* __restrict__ wpb,
                                __hip_bfloat16* __restrict__ wdb) {
    const int i = (blockIdx.x * 256 + threadIdx.x) * 4;
    if (i >= R4) return;
    if (i < R0) {
        *reinterpret_cast<ushort4*>(xa + i) = cvt4(*(const float4*)(x1 + i));
    } else if (i < R1) {
        int j = i - R0;
        *reinterpret_cast<ushort4*>(wb1 + j) = cvt4(*(const float4*)(w_in + j));
    } else if (i < R2) {
        int j = i - R1;
        *reinterpret_cast<ushort4*>(wob + j) = cvt4(*(const float4*)(w_out + j));
    } else if (i < R3) {
        int j = i - R2; int e = j >> 11;
        float4 v = (e < 96) ? *(const float4*)(w_xp + j) : float4{0.f, 0.f, 0.f, 0.f};
        *reinterpret_cast<ushort4*>(wpb + j) = cvt4(v);
    } else {
        int j = i - R3;
        *reinterpret_cast<ushort4*>(wdb + j) = cvt4(*(const float4*)(w_dt + j));
    }
}

// ---------------------------------------------------------------------------
// Depthwise causal conv1d (k=4, left pad 3) + bias + SiLU. Fully coalesced.
// ---------------------------------------------------------------------------
__global__ void conv_silu_kernel(const float* __restrict__ xz,
                                 const float* __restrict__ conv_w,
                                 const float* __restrict__ conv_b,
                                 float* __restrict__ xs,
                                 __hip_bfloat16* __restrict__ xsb) {
    int idx = blockIdx.x * blockDim.x + threadIdx.x;  // (b*L + l)*DINNER + d
    int d = idx & (DINNER - 1);
    int l = (idx >> 11) & (SEQL - 1);
    int b = idx >> 19;
    const float w0 = conv_w[d * 4 + 0];
    const float w1 = conv_w[d * 4 + 1];
    const float w2 = conv_w[d * 4 + 2];
    const float w3 = conv_w[d * 4 + 3];
    float acc = conv_b[d];
    const size_t base = (size_t)(b * SEQL) * (2 * DINNER) + d;
    if (l >= 3) acc += w0 * xz[base + (size_t)(l - 3) * (2 * DINNER)];
    if (l >= 2) acc += w1 * xz[base + (size_t)(l - 2) * (2 * DINNER)];
    if (l >= 1) acc += w2 * xz[base + (size_t)(l - 1) * (2 * DINNER)];
    acc += w3 * xz[base + (size_t)l * (2 * DINNER)];
    float v = acc / (1.f + __expf(-acc));
    xs[idx] = v;
    xsb[idx] = __float2bfloat16(v);
}

// ---------------------------------------------------------------------------
// 16-lane row sum via DPP row_ror rotations (no DS ops).
// ---------------------------------------------------------------------------
__device__ __forceinline__ float row_reduce16(float x) {
    x += __int_as_float(__builtin_amdgcn_update_dpp(0, __float_as_int(x), 0x128, 0xF, 0xF, true));
    x += __int_as_float(__builtin_amdgcn_update_dpp(0, __float_as_int(x), 0x124, 0xF, 0xF, true));
    x += __int_as_float(__builtin_amdgcn_update_dpp(0, __float_as_int(x), 0x122, 0xF, 0xF, true));
    x += __int_as_float(__builtin_amdgcn_update_dpp(0, __float_as_int(x), 0x121, 0xF, 0xF, true));
    return x;
}

// ---------------------------------------------------------------------------
// Chunk-parallel scan, phase A: per-chunk local recurrence (reads xs).
// Grid (128, B, 3): chunk 3's carry is never consumed -> not computed.
// ---------------------------------------------------------------------------
__global__ __launch_bounds__(256) void scan_carry_kernel(const float* __restrict__ delta,
                                                         const float* __restrict__ xs,
                                                         const float* __restrict__ xdbl,
                                                         const float* __restrict__ A_log,
                                                         float* __restrict__ carryL,
                                                         float* __restrict__ carryP) {
    __shared__ float sDU[CH][16][2];   // [l][dl][{dv, dv*xv}]
    __shared__ float sB[CH][16];       // [l][n]
    const int b = blockIdx.y, c = blockIdx.z, dg = blockIdx.x;
    const int t = threadIdx.x;
    const int dl = t >> 4, n = t & 15;
    const int d = dg * 16 + dl;
    const float a = -__expf(A_log[d * DSTATE + n]);
    const int srow = t >> 4, scol = t & 15;
    const int sd = dg * 16 + scol;
    const int rowbase = b * SEQL + c * CH;
    #pragma unroll
    for (int i = 0; i < 4; ++i) {
        const int row = rowbase + i * 16 + srow;
        const float dv = delta[(size_t)row * DINNER + sd];
        const float xv = xs[(size_t)row * DINNER + sd];
        sDU[i * 16 + srow][scol][0] = dv;
        sDU[i * 16 + srow][scol][1] = dv * xv;
        sB[i * 16 + srow][scol] = xdbl[row * 128 + 64 + scol];
    }
    __syncthreads();
    float h = 0.f, P = 1.f;
    #pragma unroll 16
    for (int l = 0; l < CH; ++l) {
        const float e = __expf(sDU[l][dl][0] * a);
        h = e * h + sDU[l][dl][1] * sB[l][n];
        P *= e;
    }
    const size_t ci = (((size_t)(b * NCHUNK + c)) * DINNER + d) * DSTATE + n;
    carryL[ci] = h;
    carryP[ci] = P;
}

// ---------------------------------------------------------------------------
// Chunk-parallel scan, phase B: combine carries (h = P_j h + L_j, j < c) then
// run the 64-step scan with y output (+D*xs, *silu(res), bf16).
// ---------------------------------------------------------------------------
__global__ __launch_bounds__(256) void scan_apply_kernel(const float* __restrict__ delta,
                                                         const float* __restrict__ xs,
                                                         const float* __restrict__ xdbl,
                                                         const float* __restrict__ xz,
                                                         const float* __restrict__ A_log,
                                                         const float* __restrict__ Dp,
                                                         const float* __restrict__ carryL,
                                                         const float* __restrict__ carryP,
                                                         __hip_bfloat16* __restrict__ ybb) {
    __shared__ float sDU[CH][16][2];   // [l][dl][{dv, dv*xv}]
    __shared__ float sBC[CH][16][2];   // [l][n][{B, C}]
    __shared__ float sGW[CH][16][2];   // [l][dl][{g, D*xv*g}]
    const int b = blockIdx.y, c = blockIdx.z, dg = blockIdx.x;
    const int t = threadIdx.x;
    const int dl = t >> 4, n = t & 15;
    const int d = dg * 16 + dl;
    const float a = -__expf(A_log[d * DSTATE + n]);
    const int srow = t >> 4, scol = t & 15;
    const int sd = dg * 16 + scol;
    const float Dstage = Dp[sd];
    const int rowbase = b * SEQL + c * CH;
    #pragma unroll
    for (int i = 0; i < 4; ++i) {
        const int row = rowbase + i * 16 + srow;
        const float dv = delta[(size_t)row * DINNER + sd];
        const float xv = xs[(size_t)row * DINNER + sd];
        const float r  = xz[(size_t)row * (2 * DINNER) + DINNER + sd];
        const float g = r / (1.f + __expf(-r));
        const int lr_ = i * 16 + srow;
        sDU[lr_][scol][0] = dv;
        sDU[lr_][scol][1] = dv * xv;
        sGW[lr_][scol][0] = g;
        sGW[lr_][scol][1] = Dstage * xv * g;
        sBC[lr_][scol][0] = xdbl[row * 128 + 64 + scol];
        sBC[lr_][scol][1] = xdbl[row * 128 + 80 + scol];
    }
    __syncthreads();
    float h = 0.f;
    for (int j = 0; j < c; ++j) {
        const size_t ci = (((size_t)(b * NCHUNK + j)) * DINNER + d) * DSTATE + n;
        h = carryP[ci] * h + carryL[ci];
    }
    #pragma unroll 16
    for (int l = 0; l < CH; ++l) {
        const float e = __expf(sDU[l][dl][0] * a);
        h = e * h + sDU[l][dl][1] * sBC[l][n][0];
        float pr = row_reduce16(h * sBC[l][n][1]);
        if (n == 0) {
            const float y = pr * sGW[l][dl][0] + sGW[l][dl][1];
            ybb[(size_t)(rowbase + l) * DINNER + d] = __float2bfloat16(y);
        }
    }
}

// ---------------------------------------------------------------------------
// LayerNorm over last dim (1024), fused 4-way split-K reduce of out_proj
// partials. block per row, 256 threads x 4 elems.
// ---------------------------------------------------------------------------
__global__ __launch_bounds__(256) void ln_kernel(const float* __restrict__ opart,
                                                 const float* __restrict__ lw,
                                                 const float* __restrict__ lb,
                                                 float* __restrict__ out) {
    __shared__ float red[8];
    const int row = blockIdx.x;
    const int t = threadIdx.x;
    float v[4];
    float s = 0.f, s2 = 0.f;
    #pragma unroll
    for (int i = 0; i < 4; ++i) {
        const int c = t + 256 * i;
        float acc = 0.f;
        #pragma unroll
        for (int z = 0; z < 4; ++z)
            acc += opart[(size_t)z * (1024 * 1024) + (size_t)row * OUTC + c];
        v[i] = acc;
        s += acc;
        s2 += acc * acc;
    }
    #pragma unroll
    for (int o = 32; o; o >>= 1) {
        s += __shfl_down(s, o);
        s2 += __shfl_down(s2, o);
    }
    const int wid = t >> 6;
    if ((t & 63) == 0) { red[wid] = s; red[4 + wid] = s2; }
    __syncthreads();
    if (t == 0) {
        float ts = red[0] + red[1] + red[2] + red[3];
        float ts2 = red[4] + red[5] + red[6] + red[7];
        float mu = ts * (1.f / OUTC);
        float var = ts2 * (1.f / OUTC) - mu * mu;
        red[0] = mu;
        red[1] = rsqrtf(var + 1e-5f);
    }
    __syncthreads();
    const float mu = red[0], rs = red[1];
    #pragma unroll
    for (int i = 0; i < 4; ++i) {
        const int c = t + 256 * i;
        out[(size_t)row * OUTC + c] = (v[i] - mu) * rs * lw[c] + lb[c];
    }
}

// ---------------------------------------------------------------------------
extern "C" void kernel_launch(void* const* d_in, const int* in_sizes, int n_in,
                              void* d_out, int out_size, void* d_ws, size_t ws_size,
                              hipStream_t stream) {
    const float* x1        = (const float*)d_in[0];   // (1024,1024)
    const float* in_proj_w = (const float*)d_in[1];   // (4096,1024)
    const float* conv_w    = (const float*)d_in[2];   // (2048,1,4)
    const float* conv_b    = (const float*)d_in[3];   // (2048,)
    const float* x_proj_w  = (const float*)d_in[4];   // (96,2048)
    const float* dt_proj_w = (const float*)d_in[5];   // (2048,64)
    const float* dt_proj_b = (const float*)d_in[6];   // (2048,)
    const float* A_log     = (const float*)d_in[7];   // (2048,16)
    const float* Dp        = (const float*)d_in[8];   // (2048,)
    const float* out_proj_w= (const float*)d_in[9];   // (1024,2048)
    const float* ln_w      = (const float*)d_in[10];  // (1024,)
    const float* ln_b      = (const float*)d_in[11];  // (1024,)
    float* out = (float*)d_out;

    // workspace carve-up
    char* p = (char*)d_ws;
    __hip_bfloat16* xa    = (__hip_bfloat16*)p; p += (size_t)1024 * 1024 * 2;  // 2 MB
    __hip_bfloat16* wb1   = (__hip_bfloat16*)p; p += (size_t)4096 * 1024 * 2;  // 8 MB
    __hip_bfloat16* wpb   = (__hip_bfloat16*)p; p += (size_t)128 * 2048 * 2;   // 0.5 MB
    __hip_bfloat16* wob   = (__hip_bfloat16*)p; p += (size_t)1024 * 2048 * 2;  // 4 MB
    __hip_bfloat16* wdb   = (__hip_bfloat16*)p; p += (size_t)2048 * 64 * 2;    // 0.25 MB
    __hip_bfloat16* xsb   = (__hip_bfloat16*)p; p += (size_t)1024 * 2048 * 2;  // 4 MB
    __hip_bfloat16* ybb   = (__hip_bfloat16*)p; p += (size_t)1024 * 2048 * 2;  // 4 MB
    __hip_bfloat16* xdblb = (__hip_bfloat16*)p; p += (size_t)1024 * 128 * 2;   // 0.25 MB
    float* xz    = (float*)p; p += (size_t)1024 * 4096 * 4;                    // 16 MB
    float* xs    = (float*)p; p += (size_t)1024 * 2048 * 4;                    // 8 MB
    float* xdbl  = (float*)p; p += (size_t)1024 * 128 * 4;                     // 0.5 MB
    float* xpart = (float*)p; p += (size_t)XPZ * 1024 * 128 * 4;               // 8 MB
    float* delta = (float*)p; p += (size_t)1024 * 2048 * 4;                    // 8 MB
    float* carryL = (float*)p; p += (size_t)BATCH * NCHUNK * DINNER * DSTATE * 4; // 2 MB
    float* carryP = (float*)p; p += (size_t)BATCH * NCHUNK * DINNER * DSTATE * 4; // 2 MB
    // out_proj partials (16 MB) alias xz: scan B (last reader of xz) precedes
    // out_proj in stream order.
    float* opart = xz;

    // 0. fused bf16 casts (float4-vectorized)
    cast_all_kernel<<<(R4 / 4 + 255) / 256, 256, 0, stream>>>(x1, in_proj_w, out_proj_w,
                                                              x_proj_w, dt_proj_w,
                                                              xa, wb1, wob, wpb, wdb);
    // 1. in_proj: xz = xa @ wb1^T  (1024 x 4096, K=1024) — 512 blocks (2/CU)
    gemm_n64<<<dim3(64, 8, 1), 256, 0, stream>>>(xa, wb1, xz,
                                                 NROWS, 2 * DINNER, DMODEL, DMODEL, DMODEL);
    // 2. depthwise causal conv + SiLU -> xs (fp32) + xsb (bf16)
    conv_silu_kernel<<<(NROWS * DINNER) / 256, 256, 0, stream>>>(xz, conv_w, conv_b, xs, xsb);
    // 3. x_proj: xpart[z] = xsb @ wpb^T (1024 x 128, K=2048 split 16) — 256 blocks
    gemm_n64<<<dim3(2, 8, XPZ), 256, 0, stream>>>(xsb, wpb, xpart,
                                                  NROWS, 128, DINNER, DINNER, DINNER);
    // 4. reduce partials -> xdbl fp32 + xdblb bf16
    xdbl_reduce_kernel<<<(1024 * 128) / 256, 256, 0, stream>>>(xpart, xdbl, xdblb);
    // 5. dt_proj + softplus -> delta (MFMA, K=64)
    gemm_dtsp<<<dim3(16, 8), 256, 0, stream>>>(xdblb, wdb, dt_proj_b, delta);
    // 6a. scan phase A: per-chunk carries (chunks 0..2 only; 1536 blocks)
    scan_carry_kernel<<<dim3(DINNER / 16, BATCH, NCHUNK - 1), 256, 0, stream>>>(
        delta, xs, xdbl, A_log, carryL, carryP);
    // 6b. scan phase B: combine + apply + gate -> ybb (bf16) (2048 blocks)
    scan_apply_kernel<<<dim3(DINNER / 16, BATCH, NCHUNK), 256, 0, stream>>>(
        delta, xs, xdbl, xz, A_log, Dp, carryL, carryP, ybb);
    // 7. out_proj: opart[z] = ybb @ wob^T (1024 x 1024, K=2048 split 4) — 512 blocks
    gemm_n64<<<dim3(16, 8, 4), 256, 0, stream>>>(ybb, wob, opart,
                                                 NROWS, OUTC, DINNER, DINNER, DINNER);
    // 8. LayerNorm (+ split-K reduce) -> out
    ln_kernel<<<NROWS, 256, 0, stream>>>(opart, ln_w, ln_b, out);
}